// Round 1
// baseline (353.277 us; speedup 1.0000x reference)
//
#include <hip/hip_runtime.h>
#include <hip/hip_bf16.h>

// ---------- types ----------
typedef __bf16 bf16x8 __attribute__((ext_vector_type(8)));
typedef float  f32x4  __attribute__((ext_vector_type(4)));

// ---------- helpers ----------
__device__ __forceinline__ unsigned short f2bf(float f) {
    unsigned int u = __float_as_uint(f);
    u += 0x7fffu + ((u >> 16) & 1u);   // RNE
    return (unsigned short)(u >> 16);
}
__device__ __forceinline__ float bf2f(unsigned short b) {
    return __uint_as_float(((unsigned int)b) << 16);
}
__device__ __forceinline__ float tanh_fast(float x) {
    float e = __expf(-2.0f * fabsf(x));
    float r = (1.0f - e) / (1.0f + e);
    return copysignf(r, x);
}

// ---------- elementwise cast fp32 -> bf16 ----------
__global__ __launch_bounds__(256) void cast_f32_bf16(
    const float* __restrict__ in, unsigned short* __restrict__ out) {
    long i = ((long)blockIdx.x * 256 + threadIdx.x) * 4;
    float4 f = *(const float4*)(in + i);
    ushort4 o;
    o.x = f2bf(f.x); o.y = f2bf(f.y); o.z = f2bf(f.z); o.w = f2bf(f.w);
    *(ushort4*)(out + i) = o;
}

// ---------- small weight transpose: in (R x C) fp32 -> out (C x R) bf16 ----------
__global__ void transpose_w_f32_bf16(
    const float* __restrict__ in, unsigned short* __restrict__ out, int R, int C) {
    int idx = blockIdx.x * 256 + threadIdx.x;
    if (idx >= R * C) return;
    int r = idx / C, c = idx - r * C;
    out[(long)c * R + r] = f2bf(in[idx]);
}

// ---------- batched V transpose: (N,2048,512) bf16 -> (N,512,2048) bf16 ----------
__global__ __launch_bounds__(256) void transpose_v(
    const unsigned short* __restrict__ in, unsigned short* __restrict__ out) {
    __shared__ unsigned short t[32][33];
    const int h0 = blockIdx.x * 32, l0 = blockIdx.y * 32;
    const size_t zoff = (size_t)blockIdx.z * 2048 * 512;
    const unsigned short* ip = in + zoff;
    unsigned short* op = out + zoff;
    const int tx = threadIdx.x & 31, ty = threadIdx.x >> 5; // ty 0..7
#pragma unroll
    for (int r = 0; r < 32; r += 8)
        t[ty + r][tx] = ip[(size_t)(l0 + ty + r) * 512 + h0 + tx];
    __syncthreads();
#pragma unroll
    for (int r = 0; r < 32; r += 8)
        op[(size_t)(h0 + ty + r) * 2048 + l0 + tx] = t[tx][ty + r];
}

// ---------- in-place row softmax on bf16 S: rows of length 2048 ----------
__global__ __launch_bounds__(256) void softmax_rows(unsigned short* __restrict__ S) {
    const size_t row = (size_t)blockIdx.y * 2048 + blockIdx.x;
    unsigned short* p = S + row * 2048;
    const int t = threadIdx.x;
    uint4 raw = *(uint4*)(p + t * 8);
    unsigned int w[4] = {raw.x, raw.y, raw.z, raw.w};
    float v[8];
#pragma unroll
    for (int i = 0; i < 4; ++i) {
        v[2 * i]     = __uint_as_float((w[i] & 0xffffu) << 16);
        v[2 * i + 1] = __uint_as_float(w[i] & 0xffff0000u);
    }
    float mx = v[0];
#pragma unroll
    for (int i = 1; i < 8; ++i) mx = fmaxf(mx, v[i]);
#pragma unroll
    for (int off = 32; off > 0; off >>= 1) mx = fmaxf(mx, __shfl_xor(mx, off));
    __shared__ float red[8];
    const int wave = t >> 6, lane = t & 63;
    if (lane == 0) red[wave] = mx;
    __syncthreads();
    mx = fmaxf(fmaxf(red[0], red[1]), fmaxf(red[2], red[3]));
    float s = 0.0f;
#pragma unroll
    for (int i = 0; i < 8; ++i) { v[i] = __expf(v[i] - mx); s += v[i]; }
#pragma unroll
    for (int off = 32; off > 0; off >>= 1) s += __shfl_xor(s, off);
    if (lane == 0) red[4 + wave] = s;
    __syncthreads();
    s = red[4] + red[5] + red[6] + red[7];
    const float inv = 1.0f / s;
#pragma unroll
    for (int i = 0; i < 4; ++i) {
        unsigned int lo = f2bf(v[2 * i] * inv);
        unsigned int hi = f2bf(v[2 * i + 1] * inv);
        w[i] = lo | (hi << 16);
    }
    raw.x = w[0]; raw.y = w[1]; raw.z = w[2]; raw.w = w[3];
    *(uint4*)(p + t * 8) = raw;
}

// ---------- bt-form bf16 MFMA GEMM ----------
// C[m][n] = sum_k A[m][k] * Bt[n][k]   (A: M x K row-major, Bt: N x K row-major)
// tile 64x64, block = 4 waves in 2x2, each wave 2x2 fragments of 16x16x32.
// MODE 0: +bias -> bf16 | 1: plain -> bf16 | 2: +bias, leaky(0.2) -> bf16
// MODE 3: +bias, tanh, +resid -> fp32
template <int MODE>
__global__ __launch_bounds__(256) void gemm_bt(
    const unsigned short* __restrict__ A,
    const unsigned short* __restrict__ Bt,
    const float* __restrict__ bias,
    const float* __restrict__ resid,
    unsigned short* __restrict__ outB,
    float* __restrict__ outF,
    int K, int ldc, long sA, long sB, long sC) {
    __shared__ __bf16 As[64][72];   // +8 pad: row stride 144B -> 2-way bank alias (free)
    __shared__ __bf16 Bs[64][72];

    const int tid  = threadIdx.x;
    const int lane = tid & 63, wave = tid >> 6;
    const int m16  = lane & 15, quad = lane >> 4;
    const int wm   = (wave >> 1) << 5, wn = (wave & 1) << 5;
    const int m0   = blockIdx.x << 6, n0 = blockIdx.y << 6;
    const int ar   = tid >> 3;           // 0..31
    const int ac   = (tid & 7) << 3;     // 0,8,...,56

    const unsigned short* Ap = A + (long)blockIdx.z * sA + (long)(m0 + ar) * K + ac;
    const unsigned short* Bp = Bt + (long)blockIdx.z * sB + (long)(n0 + ar) * K + ac;
    const long rows32 = (long)K * 32;

    f32x4 acc[2][2] = {};

    for (int k0 = 0; k0 < K; k0 += 64) {
        uint4 a0 = *(const uint4*)(Ap + k0);
        uint4 a1 = *(const uint4*)(Ap + k0 + rows32);
        uint4 b0 = *(const uint4*)(Bp + k0);
        uint4 b1 = *(const uint4*)(Bp + k0 + rows32);
        __syncthreads();
        *(uint4*)&As[ar][ac]      = a0;
        *(uint4*)&As[ar + 32][ac] = a1;
        *(uint4*)&Bs[ar][ac]      = b0;
        *(uint4*)&Bs[ar + 32][ac] = b1;
        __syncthreads();
#pragma unroll
        for (int ks = 0; ks < 64; ks += 32) {
            bf16x8 af0 = *(const bf16x8*)&As[wm + m16][ks + quad * 8];
            bf16x8 af1 = *(const bf16x8*)&As[wm + 16 + m16][ks + quad * 8];
            bf16x8 bg0 = *(const bf16x8*)&Bs[wn + m16][ks + quad * 8];
            bf16x8 bg1 = *(const bf16x8*)&Bs[wn + 16 + m16][ks + quad * 8];
            acc[0][0] = __builtin_amdgcn_mfma_f32_16x16x32_bf16(af0, bg0, acc[0][0], 0, 0, 0);
            acc[0][1] = __builtin_amdgcn_mfma_f32_16x16x32_bf16(af0, bg1, acc[0][1], 0, 0, 0);
            acc[1][0] = __builtin_amdgcn_mfma_f32_16x16x32_bf16(af1, bg0, acc[1][0], 0, 0, 0);
            acc[1][1] = __builtin_amdgcn_mfma_f32_16x16x32_bf16(af1, bg1, acc[1][1], 0, 0, 0);
        }
    }

    const long zC = (long)blockIdx.z * sC;
#pragma unroll
    for (int fj = 0; fj < 2; ++fj) {
        const int col = n0 + wn + fj * 16 + m16;
        float bv = 0.0f;
        if (MODE != 1) bv = bias[col];
#pragma unroll
        for (int fi = 0; fi < 2; ++fi) {
#pragma unroll
            for (int r = 0; r < 4; ++r) {
                const int row = m0 + wm + fi * 16 + quad * 4 + r;
                float v = acc[fi][fj][r] + bv;
                const long idx = zC + (long)row * ldc + col;
                if (MODE == 2) v = v > 0.0f ? v : 0.2f * v;
                if (MODE == 3) {
                    outF[idx] = tanh_fast(v) + resid[idx];
                } else {
                    outB[idx] = f2bf(v);
                }
            }
        }
    }
}

// ---------- launch ----------
extern "C" void kernel_launch(void* const* d_in, const int* in_sizes, int n_in,
                              void* d_out, int out_size, void* d_ws, size_t ws_size,
                              hipStream_t stream) {
    const float* x       = (const float*)d_in[0];
    const float* theta_w = (const float*)d_in[1];
    const float* theta_b = (const float*)d_in[2];
    const float* phi_w   = (const float*)d_in[3];
    const float* phi_b   = (const float*)d_in[4];
    const float* psi_w   = (const float*)d_in[5];
    const float* psi_b   = (const float*)d_in[6];
    const float* r1_w    = (const float*)d_in[7];
    const float* r1_b    = (const float*)d_in[8];
    const float* r2_w    = (const float*)d_in[9];
    const float* r2_b    = (const float*)d_in[10];
    float* out = (float*)d_out;

    constexpr int  N  = 8, L = 2048, C = 512, H = 512, CH = 256;
    constexpr long NL = (long)N * L;  // 16384

    char* p = (char*)d_ws;
    auto alloc = [&](size_t bytes) { void* q = (void*)p; p += bytes; return q; };
    unsigned short* xb    = (unsigned short*)alloc(NL * C * 2);
    unsigned short* xt    = (unsigned short*)alloc(NL * H * 2);
    unsigned short* xph   = (unsigned short*)alloc(NL * H * 2);
    unsigned short* xpsi  = (unsigned short*)alloc(NL * H * 2);
    unsigned short* xpsiT = (unsigned short*)alloc(NL * H * 2);
    unsigned short* xadd  = (unsigned short*)alloc(NL * H * 2);
    unsigned short* h1    = (unsigned short*)alloc(NL * CH * 2);
    unsigned short* wThT  = (unsigned short*)alloc((long)C * H * 2);
    unsigned short* wPhT  = (unsigned short*)alloc((long)C * H * 2);
    unsigned short* wPsT  = (unsigned short*)alloc((long)C * H * 2);
    unsigned short* r1T   = (unsigned short*)alloc((long)H * CH * 2);
    unsigned short* r2T   = (unsigned short*)alloc((long)CH * C * 2);
    unsigned short* S     = (unsigned short*)alloc((long)N * L * L * 2);

    // 1. cast x -> bf16
    cast_f32_bf16<<<(int)(NL * C / 1024), 256, 0, stream>>>(x, xb);

    // 2. transpose weights (tiny)
    transpose_w_f32_bf16<<<(C * H + 255) / 256, 256, 0, stream>>>(theta_w, wThT, C, H);
    transpose_w_f32_bf16<<<(C * H + 255) / 256, 256, 0, stream>>>(phi_w, wPhT, C, H);
    transpose_w_f32_bf16<<<(C * H + 255) / 256, 256, 0, stream>>>(psi_w, wPsT, C, H);
    transpose_w_f32_bf16<<<(H * CH + 255) / 256, 256, 0, stream>>>(r1_w, r1T, H, CH);
    transpose_w_f32_bf16<<<(CH * C + 255) / 256, 256, 0, stream>>>(r2_w, r2T, CH, C);

    // 3. projections: (16384x512) @ (512x512) + b -> bf16
    dim3 gp(NL / 64, H / 64, 1);
    gemm_bt<0><<<gp, 256, 0, stream>>>(xb, wThT, theta_b, nullptr, xt,   nullptr, C, H, 0, 0, 0);
    gemm_bt<0><<<gp, 256, 0, stream>>>(xb, wPhT, phi_b,   nullptr, xph,  nullptr, C, H, 0, 0, 0);
    gemm_bt<0><<<gp, 256, 0, stream>>>(xb, wPsT, psi_b,   nullptr, xpsi, nullptr, C, H, 0, 0, 0);

    // 4. V transpose per batch: (L,H) -> (H,L)
    transpose_v<<<dim3(H / 32, L / 32, N), 256, 0, stream>>>(xpsi, xpsiT);

    // 5. S = Q @ K^T  (batched; Bt-form is natural since K rows are k-contiguous)
    gemm_bt<1><<<dim3(L / 64, L / 64, N), 256, 0, stream>>>(
        xph, xt, nullptr, nullptr, S, nullptr, H, L,
        (long)L * H, (long)L * H, (long)L * L);

    // 6. softmax rows in place
    softmax_rows<<<dim3(L, N), 256, 0, stream>>>(S);

    // 7. x_add = P @ V  (Bt = V^T)
    gemm_bt<1><<<dim3(L / 64, H / 64, N), 256, 0, stream>>>(
        S, xpsiT, nullptr, nullptr, xadd, nullptr, L, H,
        (long)L * L, (long)H * L, (long)L * H);

    // 8. h1 = leaky(x_add @ r1 + b)
    gemm_bt<2><<<dim3(NL / 64, CH / 64, 1), 256, 0, stream>>>(
        xadd, r1T, r1_b, nullptr, h1, nullptr, H, CH, 0, 0, 0);

    // 9. out = x + tanh(h1 @ r2 + b)
    gemm_bt<3><<<dim3(NL / 64, C / 64, 1), 256, 0, stream>>>(
        h1, r2T, r2_b, x, nullptr, out, CH, C, 0, 0, 0);
}

// Round 2
// 315.982 us; speedup vs baseline: 1.1180x; 1.1180x over previous
//
#include <hip/hip_runtime.h>
#include <hip/hip_bf16.h>

// ---------- types ----------
typedef __bf16 bf16x8 __attribute__((ext_vector_type(8)));
typedef float  f32x4  __attribute__((ext_vector_type(4)));
typedef __attribute__((address_space(3))) unsigned int       lds_uint;
typedef __attribute__((address_space(1))) const unsigned int glb_uint;

// ---------- helpers ----------
__device__ __forceinline__ unsigned short f2bf(float f) {
    unsigned int u = __float_as_uint(f);
    u += 0x7fffu + ((u >> 16) & 1u);   // RNE
    return (unsigned short)(u >> 16);
}
__device__ __forceinline__ float tanh_fast(float x) {
    float e = __expf(-2.0f * fabsf(x));
    float r = (1.0f - e) / (1.0f + e);
    return copysignf(r, x);
}

// ---------- elementwise cast fp32 -> bf16 ----------
__global__ __launch_bounds__(256) void cast_f32_bf16(
    const float* __restrict__ in, unsigned short* __restrict__ out) {
    long i = ((long)blockIdx.x * 256 + threadIdx.x) * 4;
    float4 f = *(const float4*)(in + i);
    ushort4 o;
    o.x = f2bf(f.x); o.y = f2bf(f.y); o.z = f2bf(f.z); o.w = f2bf(f.w);
    *(ushort4*)(out + i) = o;
}

// ---------- small weight transpose: in (R x C) fp32 -> out (C x R) bf16 ----------
__global__ void transpose_w_f32_bf16(
    const float* __restrict__ in, unsigned short* __restrict__ out, int R, int C) {
    int idx = blockIdx.x * 256 + threadIdx.x;
    if (idx >= R * C) return;
    int r = idx / C, c = idx - r * C;
    out[(long)c * R + r] = f2bf(in[idx]);
}

// ---------- batched V transpose: (N,2048,512) bf16 -> (N,512,2048) bf16 ----------
__global__ __launch_bounds__(256) void transpose_v(
    const unsigned short* __restrict__ in, unsigned short* __restrict__ out) {
    __shared__ unsigned short t[32][33];
    const int h0 = blockIdx.x * 32, l0 = blockIdx.y * 32;
    const size_t zoff = (size_t)blockIdx.z * 2048 * 512;
    const unsigned short* ip = in + zoff;
    unsigned short* op = out + zoff;
    const int tx = threadIdx.x & 31, ty = threadIdx.x >> 5; // ty 0..7
#pragma unroll
    for (int r = 0; r < 32; r += 8)
        t[ty + r][tx] = ip[(size_t)(l0 + ty + r) * 512 + h0 + tx];
    __syncthreads();
#pragma unroll
    for (int r = 0; r < 32; r += 8)
        op[(size_t)(h0 + ty + r) * 2048 + l0 + tx] = t[tx][ty + r];
}

// ---------- in-place row softmax on bf16 S: rows of length 2048 ----------
__global__ __launch_bounds__(256) void softmax_rows(unsigned short* __restrict__ S) {
    const size_t row = (size_t)blockIdx.y * 2048 + blockIdx.x;
    unsigned short* p = S + row * 2048;
    const int t = threadIdx.x;
    uint4 raw = *(uint4*)(p + t * 8);
    unsigned int w[4] = {raw.x, raw.y, raw.z, raw.w};
    float v[8];
#pragma unroll
    for (int i = 0; i < 4; ++i) {
        v[2 * i]     = __uint_as_float((w[i] & 0xffffu) << 16);
        v[2 * i + 1] = __uint_as_float(w[i] & 0xffff0000u);
    }
    float mx = v[0];
#pragma unroll
    for (int i = 1; i < 8; ++i) mx = fmaxf(mx, v[i]);
#pragma unroll
    for (int off = 32; off > 0; off >>= 1) mx = fmaxf(mx, __shfl_xor(mx, off));
    __shared__ float red[8];
    const int wave = t >> 6, lane = t & 63;
    if (lane == 0) red[wave] = mx;
    __syncthreads();
    mx = fmaxf(fmaxf(red[0], red[1]), fmaxf(red[2], red[3]));
    float s = 0.0f;
#pragma unroll
    for (int i = 0; i < 8; ++i) { v[i] = __expf(v[i] - mx); s += v[i]; }
#pragma unroll
    for (int off = 32; off > 0; off >>= 1) s += __shfl_xor(s, off);
    if (lane == 0) red[4 + wave] = s;
    __syncthreads();
    s = red[4] + red[5] + red[6] + red[7];
    const float inv = 1.0f / s;
#pragma unroll
    for (int i = 0; i < 4; ++i) {
        unsigned int lo = f2bf(v[2 * i] * inv);
        unsigned int hi = f2bf(v[2 * i + 1] * inv);
        w[i] = lo | (hi << 16);
    }
    raw.x = w[0]; raw.y = w[1]; raw.z = w[2]; raw.w = w[3];
    *(uint4*)(p + t * 8) = raw;
}

// ---------- 128x128-tile bt-form bf16 MFMA GEMM (m97 structure) ----------
// C[m][n] = sum_k A[m][k] * Bt[n][k]   (A: M x K row-major, Bt: N x K row-major)
// 256 threads = 4 waves in 2x2; each wave computes 64x64 via 4x4 frags of 16x16x32.
// Staging: global_load_lds width=16, XOR-swizzled k-units so fragment ds_read_b128
// hits all 32 banks at 2 lanes/bank (free aliasing).
// MODE 0: +bias -> bf16 | 1: plain -> bf16 | 2: +bias, leaky(0.2) -> bf16
// MODE 3: +bias, tanh, +resid -> fp32
template <int MODE>
__global__ __launch_bounds__(256) void gemm128(
    const unsigned short* __restrict__ A,
    const unsigned short* __restrict__ Bt,
    const float* __restrict__ bias,
    const float* __restrict__ resid,
    unsigned short* __restrict__ outB,
    float* __restrict__ outF,
    int K, int ldc, long sA, long sB, long sC) {
    __shared__ __bf16 As[128 * 64];   // row stride 64 bf16 = 128 B; swizzle handles banks
    __shared__ __bf16 Bs[128 * 64];

    const int tid  = threadIdx.x;
    const int lane = tid & 63, wave = tid >> 6;
    const int m16  = lane & 15, quad = lane >> 4;
    const int wm   = (wave >> 1) << 6, wn = (wave & 1) << 6;
    const int m0   = blockIdx.x << 7, n0 = blockIdx.y << 7;

    const int srow  = lane >> 3;                 // 0..7 row within an 8-row issue
    const int sunit = lane & 7;                  // 16B-unit slot within row
    const int uswz  = sunit ^ srow;              // global k-unit this lane fetches

    const unsigned short* Abase = A  + (long)blockIdx.z * sA + (long)m0 * K;
    const unsigned short* Bbase = Bt + (long)blockIdx.z * sB + (long)n0 * K;
    // per-lane global row/col for staging (wave w covers tile rows w*32..w*32+31)
    const int stR = (wave << 5) + srow;          // + i*8 per issue
    const long gOffA0 = (long)stR * K + (uswz << 3);

    f32x4 acc[4][4] = {};

    for (int k0 = 0; k0 < K; k0 += 64) {
        __syncthreads();   // all waves done reading previous tile
#pragma unroll
        for (int i = 0; i < 4; ++i) {
            const unsigned short* gp = Abase + gOffA0 + (long)(i << 3) * K + k0;
            __bf16* lp = &As[(((wave << 5) + (i << 3)) << 6)];   // wave-uniform
            __builtin_amdgcn_global_load_lds((glb_uint*)gp, (lds_uint*)lp, 16, 0, 0);
        }
#pragma unroll
        for (int i = 0; i < 4; ++i) {
            const unsigned short* gp = Bbase + gOffA0 + (long)(i << 3) * K + k0;
            __bf16* lp = &Bs[(((wave << 5) + (i << 3)) << 6)];
            __builtin_amdgcn_global_load_lds((glb_uint*)gp, (lds_uint*)lp, 16, 0, 0);
        }
        __syncthreads();   // drains vmcnt: tiles resident
#pragma unroll
        for (int ks = 0; ks < 2; ++ks) {
            bf16x8 af[4], bg[4];
#pragma unroll
            for (int f = 0; f < 4; ++f) {
                const int m  = wm + (f << 4) + m16;
                const int n  = wn + (f << 4) + m16;
                const int cu = (ks << 2) + quad;               // wanted k-unit
                af[f] = *(const bf16x8*)&As[(m << 6) + ((cu ^ (m & 7)) << 3)];
                bg[f] = *(const bf16x8*)&Bs[(n << 6) + ((cu ^ (n & 7)) << 3)];
            }
#pragma unroll
            for (int fi = 0; fi < 4; ++fi)
#pragma unroll
                for (int fj = 0; fj < 4; ++fj)
                    acc[fi][fj] = __builtin_amdgcn_mfma_f32_16x16x32_bf16(
                        af[fi], bg[fj], acc[fi][fj], 0, 0, 0);
        }
    }

    const long zC = (long)blockIdx.z * sC;
#pragma unroll
    for (int fj = 0; fj < 4; ++fj) {
        const int col = n0 + wn + (fj << 4) + m16;
        float bv = 0.0f;
        if (MODE != 1) bv = bias[col];
#pragma unroll
        for (int fi = 0; fi < 4; ++fi) {
#pragma unroll
            for (int r = 0; r < 4; ++r) {
                const int row = m0 + wm + (fi << 4) + (quad << 2) + r;
                float v = acc[fi][fj][r] + bv;
                const long idx = zC + (long)row * ldc + col;
                if (MODE == 2) v = v > 0.0f ? v : 0.2f * v;
                if (MODE == 3) {
                    outF[idx] = tanh_fast(v) + resid[idx];
                } else {
                    outB[idx] = f2bf(v);
                }
            }
        }
    }
}

// ---------- launch ----------
extern "C" void kernel_launch(void* const* d_in, const int* in_sizes, int n_in,
                              void* d_out, int out_size, void* d_ws, size_t ws_size,
                              hipStream_t stream) {
    const float* x       = (const float*)d_in[0];
    const float* theta_w = (const float*)d_in[1];
    const float* theta_b = (const float*)d_in[2];
    const float* phi_w   = (const float*)d_in[3];
    const float* phi_b   = (const float*)d_in[4];
    const float* psi_w   = (const float*)d_in[5];
    const float* psi_b   = (const float*)d_in[6];
    const float* r1_w    = (const float*)d_in[7];
    const float* r1_b    = (const float*)d_in[8];
    const float* r2_w    = (const float*)d_in[9];
    const float* r2_b    = (const float*)d_in[10];
    float* out = (float*)d_out;

    constexpr int  N  = 8, L = 2048, C = 512, H = 512, CH = 256;
    constexpr long NL = (long)N * L;  // 16384

    char* p = (char*)d_ws;
    auto alloc = [&](size_t bytes) { void* q = (void*)p; p += bytes; return q; };
    unsigned short* xb    = (unsigned short*)alloc(NL * C * 2);
    unsigned short* xt    = (unsigned short*)alloc(NL * H * 2);
    unsigned short* xph   = (unsigned short*)alloc(NL * H * 2);
    unsigned short* xpsi  = (unsigned short*)alloc(NL * H * 2);
    unsigned short* xpsiT = (unsigned short*)alloc(NL * H * 2);
    unsigned short* xadd  = (unsigned short*)alloc(NL * H * 2);
    unsigned short* h1    = (unsigned short*)alloc(NL * CH * 2);
    unsigned short* wThT  = (unsigned short*)alloc((long)C * H * 2);
    unsigned short* wPhT  = (unsigned short*)alloc((long)C * H * 2);
    unsigned short* wPsT  = (unsigned short*)alloc((long)C * H * 2);
    unsigned short* r1T   = (unsigned short*)alloc((long)H * CH * 2);
    unsigned short* r2T   = (unsigned short*)alloc((long)CH * C * 2);
    unsigned short* S     = (unsigned short*)alloc((long)N * L * L * 2);

    // 1. cast x -> bf16
    cast_f32_bf16<<<(int)(NL * C / 1024), 256, 0, stream>>>(x, xb);

    // 2. transpose weights (tiny)
    transpose_w_f32_bf16<<<(C * H + 255) / 256, 256, 0, stream>>>(theta_w, wThT, C, H);
    transpose_w_f32_bf16<<<(C * H + 255) / 256, 256, 0, stream>>>(phi_w, wPhT, C, H);
    transpose_w_f32_bf16<<<(C * H + 255) / 256, 256, 0, stream>>>(psi_w, wPsT, C, H);
    transpose_w_f32_bf16<<<(H * CH + 255) / 256, 256, 0, stream>>>(r1_w, r1T, H, CH);
    transpose_w_f32_bf16<<<(CH * C + 255) / 256, 256, 0, stream>>>(r2_w, r2T, CH, C);

    // 3. projections: (16384x512) @ (512x512)^T-form + b -> bf16
    dim3 gp(NL / 128, H / 128, 1);
    gemm128<0><<<gp, 256, 0, stream>>>(xb, wThT, theta_b, nullptr, xt,   nullptr, C, H, 0, 0, 0);
    gemm128<0><<<gp, 256, 0, stream>>>(xb, wPhT, phi_b,   nullptr, xph,  nullptr, C, H, 0, 0, 0);
    gemm128<0><<<gp, 256, 0, stream>>>(xb, wPsT, psi_b,   nullptr, xpsi, nullptr, C, H, 0, 0, 0);

    // 4. V transpose per batch: (L,H) -> (H,L)
    transpose_v<<<dim3(H / 32, L / 32, N), 256, 0, stream>>>(xpsi, xpsiT);

    // 5. S = Q @ K^T  (batched)
    gemm128<1><<<dim3(L / 128, L / 128, N), 256, 0, stream>>>(
        xph, xt, nullptr, nullptr, S, nullptr, H, L,
        (long)L * H, (long)L * H, (long)L * L);

    // 6. softmax rows in place
    softmax_rows<<<dim3(L, N), 256, 0, stream>>>(S);

    // 7. x_add = P @ V  (Bt = V^T)
    gemm128<1><<<dim3(L / 128, H / 128, N), 256, 0, stream>>>(
        S, xpsiT, nullptr, nullptr, xadd, nullptr, L, H,
        (long)L * L, (long)H * L, (long)L * H);

    // 8. h1 = leaky(x_add @ r1 + b)
    gemm128<2><<<dim3(NL / 128, CH / 128, 1), 256, 0, stream>>>(
        xadd, r1T, r1_b, nullptr, h1, nullptr, H, CH, 0, 0, 0);

    // 9. out = x + tanh(h1 @ r2 + b)
    gemm128<3><<<dim3(NL / 128, C / 128, 1), 256, 0, stream>>>(
        h1, r2T, r2_b, x, nullptr, out, CH, C, 0, 0, 0);
}

// Round 3
// 282.560 us; speedup vs baseline: 1.2503x; 1.1183x over previous
//
#include <hip/hip_runtime.h>
#include <hip/hip_bf16.h>

// ---------- types ----------
typedef __bf16 bf16x8 __attribute__((ext_vector_type(8)));
typedef float  f32x4  __attribute__((ext_vector_type(4)));
typedef __attribute__((address_space(3))) unsigned int       lds_uint;
typedef __attribute__((address_space(1))) const unsigned int glb_uint;

// ---------- helpers ----------
__device__ __forceinline__ unsigned short f2bf(float f) {
    unsigned int u = __float_as_uint(f);
    u += 0x7fffu + ((u >> 16) & 1u);   // RNE
    return (unsigned short)(u >> 16);
}
__device__ __forceinline__ float bf2f(unsigned short b) {
    return __uint_as_float(((unsigned int)b) << 16);
}
__device__ __forceinline__ float tanh_fast(float x) {
    float e = __expf(-2.0f * fabsf(x));
    float r = (1.0f - e) / (1.0f + e);
    return copysignf(r, x);
}

// ---------- prep: cast x->bf16, transpose 5 weights, concat 3 biases ----------
// grid.x = 8192 (cast) + 1024*3 (proj weights) + 512 (r1) + 512 (r2) + 6 (bias)
__global__ __launch_bounds__(256) void prep(
    const float* __restrict__ x,
    const float* __restrict__ theta_w, const float* __restrict__ phi_w,
    const float* __restrict__ psi_w,   const float* __restrict__ r1_w,
    const float* __restrict__ r2_w,
    const float* __restrict__ theta_b, const float* __restrict__ phi_b,
    const float* __restrict__ psi_b,
    unsigned short* __restrict__ xb, unsigned short* __restrict__ wCatT,
    unsigned short* __restrict__ r1T, unsigned short* __restrict__ r2T,
    float* __restrict__ bCat) {
    const int b = blockIdx.x, t = threadIdx.x;
    if (b < 8192) {                       // cast 8M floats
        long i = ((long)b * 256 + t) * 4;
        float4 f = *(const float4*)(x + i);
        ushort4 o;
        o.x = f2bf(f.x); o.y = f2bf(f.y); o.z = f2bf(f.z); o.w = f2bf(f.w);
        *(ushort4*)(xb + i) = o;
    } else if (b < 11264) {               // proj weights (512x512 each)
        const int sel = (b - 8192) >> 10;               // 0,1,2
        const int idx = ((b - 8192) & 1023) * 256 + t;  // < 262144
        const float* w = sel == 0 ? theta_w : (sel == 1 ? phi_w : psi_w);
        const int r = idx >> 9, c = idx & 511;
        wCatT[(long)(sel * 512 + c) * 512 + r] = f2bf(w[idx]);
    } else if (b < 11776) {               // r1 (512x256)
        const int idx = (b - 11264) * 256 + t;
        const int r = idx >> 8, c = idx & 255;
        r1T[(long)c * 512 + r] = f2bf(r1_w[idx]);
    } else if (b < 12288) {               // r2 (256x512)
        const int idx = (b - 11776) * 256 + t;
        const int r = idx >> 9, c = idx & 511;
        r2T[(long)c * 256 + r] = f2bf(r2_w[idx]);
    } else {                              // bias concat (1536)
        const int i = (b - 12288) * 256 + t;
        if (i < 1536)
            bCat[i] = i < 512 ? theta_b[i] : (i < 1024 ? phi_b[i - 512] : psi_b[i - 1024]);
    }
}

// ---------- batched V transpose + fp8 cast: (L,1536-strided bf16) -> (512,2048) fp8 ----------
__global__ __launch_bounds__(256) void transpose_v_fp8(
    const unsigned short* __restrict__ in,     // xproj + 1024, row stride 1536
    unsigned char* __restrict__ out) {         // (N,512,2048) fp8
    __shared__ unsigned short tl[32][33];
    const int h0 = blockIdx.x * 32, l0 = blockIdx.y * 32;
    const unsigned short* ip = in + (size_t)blockIdx.z * 2048 * 1536;
    unsigned char* op = out + (size_t)blockIdx.z * 512 * 2048;
    const int tx = threadIdx.x & 31, ty = threadIdx.x >> 5;  // ty 0..7
#pragma unroll
    for (int r = 0; r < 32; r += 8)
        tl[ty + r][tx] = ip[(size_t)(l0 + ty + r) * 1536 + h0 + tx];
    __syncthreads();
    const int hh = threadIdx.x >> 3, j = threadIdx.x & 7;   // hh 0..31, j 0..7
    float f0 = bf2f(tl[j * 4 + 0][hh]), f1 = bf2f(tl[j * 4 + 1][hh]);
    float f2 = bf2f(tl[j * 4 + 2][hh]), f3 = bf2f(tl[j * 4 + 3][hh]);
    int w = __builtin_amdgcn_cvt_pk_fp8_f32(f0, f1, 0, false);
    w = __builtin_amdgcn_cvt_pk_fp8_f32(f2, f3, w, true);
    *(unsigned int*)(op + (size_t)(h0 + hh) * 2048 + l0 + j * 4) = (unsigned int)w;
}

// ---------- row softmax: read bf16 S row, write fp8 P in-place (first half of row) ----------
__global__ __launch_bounds__(256) void softmax_fp8(unsigned short* __restrict__ S) {
    const size_t row = (size_t)blockIdx.y * 2048 + blockIdx.x;
    unsigned short* p = S + row * 2048;
    const int t = threadIdx.x;
    uint4 raw = *(uint4*)(p + t * 8);
    unsigned int w[4] = {raw.x, raw.y, raw.z, raw.w};
    float v[8];
#pragma unroll
    for (int i = 0; i < 4; ++i) {
        v[2 * i]     = __uint_as_float((w[i] & 0xffffu) << 16);
        v[2 * i + 1] = __uint_as_float(w[i] & 0xffff0000u);
    }
    float mx = v[0];
#pragma unroll
    for (int i = 1; i < 8; ++i) mx = fmaxf(mx, v[i]);
#pragma unroll
    for (int off = 32; off > 0; off >>= 1) mx = fmaxf(mx, __shfl_xor(mx, off));
    __shared__ float red[8];
    const int wave = t >> 6, lane = t & 63;
    if (lane == 0) red[wave] = mx;
    __syncthreads();
    mx = fmaxf(fmaxf(red[0], red[1]), fmaxf(red[2], red[3]));
    float s = 0.0f;
#pragma unroll
    for (int i = 0; i < 8; ++i) { v[i] = __expf(v[i] - mx); s += v[i]; }
#pragma unroll
    for (int off = 32; off > 0; off >>= 1) s += __shfl_xor(s, off);
    if (lane == 0) red[4 + wave] = s;
    __syncthreads();
    s = red[4] + red[5] + red[6] + red[7];
    const float inv = 1.0f / s;
    int o0 = __builtin_amdgcn_cvt_pk_fp8_f32(v[0] * inv, v[1] * inv, 0, false);
    o0 = __builtin_amdgcn_cvt_pk_fp8_f32(v[2] * inv, v[3] * inv, o0, true);
    int o1 = __builtin_amdgcn_cvt_pk_fp8_f32(v[4] * inv, v[5] * inv, 0, false);
    o1 = __builtin_amdgcn_cvt_pk_fp8_f32(v[6] * inv, v[7] * inv, o1, true);
    uint2 ov; ov.x = (unsigned int)o0; ov.y = (unsigned int)o1;
    *(uint2*)((unsigned char*)p + t * 8) = ov;   // writes after barrier #2; reads were before barrier #1
}

// ---------- 128x128-tile bt-form bf16 MFMA GEMM (m97 structure) ----------
// C[m][n] = sum_k A[m][k] * Bt[n][k]; lda/ldb = row pitch in elements.
// MODE 0: +bias -> bf16 | 1: plain -> bf16 | 2: +bias, leaky(0.2) -> bf16
// MODE 3: +bias, tanh, +resid -> fp32
template <int MODE>
__global__ __launch_bounds__(256) void gemm128(
    const unsigned short* __restrict__ A,
    const unsigned short* __restrict__ Bt,
    const float* __restrict__ bias,
    const float* __restrict__ resid,
    unsigned short* __restrict__ outB,
    float* __restrict__ outF,
    int K, int lda, int ldb, int ldc, long sA, long sB, long sC) {
    __shared__ __bf16 As[128 * 64];
    __shared__ __bf16 Bs[128 * 64];

    const int tid  = threadIdx.x;
    const int lane = tid & 63, wave = tid >> 6;
    const int m16  = lane & 15, quad = lane >> 4;
    const int wm   = (wave >> 1) << 6, wn = (wave & 1) << 6;
    const int m0   = blockIdx.x << 7, n0 = blockIdx.y << 7;

    const int srow  = lane >> 3;
    const int uswz  = (lane & 7) ^ srow;

    const unsigned short* Abase = A  + (long)blockIdx.z * sA + (long)m0 * lda;
    const unsigned short* Bbase = Bt + (long)blockIdx.z * sB + (long)n0 * ldb;
    const int stR = (wave << 5) + srow;
    const long gA0 = (long)stR * lda + (uswz << 3);
    const long gB0 = (long)stR * ldb + (uswz << 3);

    f32x4 acc[4][4] = {};

    for (int k0 = 0; k0 < K; k0 += 64) {
        __syncthreads();
#pragma unroll
        for (int i = 0; i < 4; ++i) {
            const unsigned short* gp = Abase + gA0 + (long)(i << 3) * lda + k0;
            __bf16* lp = &As[(((wave << 5) + (i << 3)) << 6)];
            __builtin_amdgcn_global_load_lds((glb_uint*)gp, (lds_uint*)lp, 16, 0, 0);
        }
#pragma unroll
        for (int i = 0; i < 4; ++i) {
            const unsigned short* gp = Bbase + gB0 + (long)(i << 3) * ldb + k0;
            __bf16* lp = &Bs[(((wave << 5) + (i << 3)) << 6)];
            __builtin_amdgcn_global_load_lds((glb_uint*)gp, (lds_uint*)lp, 16, 0, 0);
        }
        __syncthreads();
#pragma unroll
        for (int ks = 0; ks < 2; ++ks) {
            bf16x8 af[4], bg[4];
#pragma unroll
            for (int f = 0; f < 4; ++f) {
                const int m  = wm + (f << 4) + m16;
                const int n  = wn + (f << 4) + m16;
                const int cu = (ks << 2) + quad;
                af[f] = *(const bf16x8*)&As[(m << 6) + ((cu ^ (m & 7)) << 3)];
                bg[f] = *(const bf16x8*)&Bs[(n << 6) + ((cu ^ (n & 7)) << 3)];
            }
#pragma unroll
            for (int fi = 0; fi < 4; ++fi)
#pragma unroll
                for (int fj = 0; fj < 4; ++fj)
                    acc[fi][fj] = __builtin_amdgcn_mfma_f32_16x16x32_bf16(
                        af[fi], bg[fj], acc[fi][fj], 0, 0, 0);
        }
    }

    const long zC = (long)blockIdx.z * sC;
#pragma unroll
    for (int fj = 0; fj < 4; ++fj) {
        const int col = n0 + wn + (fj << 4) + m16;
        float bv = 0.0f;
        if (MODE != 1) bv = bias[col];
#pragma unroll
        for (int fi = 0; fi < 4; ++fi) {
#pragma unroll
            for (int r = 0; r < 4; ++r) {
                const int row = m0 + wm + (fi << 4) + (quad << 2) + r;
                float v = acc[fi][fj][r] + bv;
                const long idx = zC + (long)row * ldc + col;
                if (MODE == 2) v = v > 0.0f ? v : 0.2f * v;
                if (MODE == 3) {
                    outF[idx] = tanh_fast(v) + resid[idx];
                } else {
                    outB[idx] = f2bf(v);
                }
            }
        }
    }
}

// ---------- fp8 P@V GEMM: 128x128 tile, BK=128 fp8 ----------
// A = P fp8, row pitch ldaB bytes (4096: fp8 packed in-place in bf16 S rows).
// Bt = V^T fp8, row pitch 2048 bytes. Out bf16, ldc 512.
__global__ __launch_bounds__(256) void gemm_pv_fp8(
    const unsigned char* __restrict__ A,
    const unsigned char* __restrict__ Bt,
    unsigned short* __restrict__ outB) {
    __shared__ unsigned char As[128 * 128];
    __shared__ unsigned char Bs[128 * 128];
    constexpr int K = 2048, ldaB = 4096, ldbB = 2048, ldc = 512;
    const long sA = (long)2048 * 4096, sB = (long)512 * 2048, sC = (long)2048 * 512;

    const int tid  = threadIdx.x;
    const int lane = tid & 63, wave = tid >> 6;
    const int m16  = lane & 15, quad = lane >> 4;
    const int wm   = (wave >> 1) << 6, wn = (wave & 1) << 6;
    const int m0   = blockIdx.x << 7, n0 = blockIdx.y << 7;

    const int srow = lane >> 3;
    const int uswz = (lane & 7) ^ srow;

    const unsigned char* Abase = A  + (long)blockIdx.z * sA + (long)m0 * ldaB;
    const unsigned char* Bbase = Bt + (long)blockIdx.z * sB + (long)n0 * ldbB;
    const int stR = (wave << 5) + srow;
    const long gA0 = (long)stR * ldaB + (uswz << 4);
    const long gB0 = (long)stR * ldbB + (uswz << 4);

    f32x4 acc[4][4] = {};

    for (int k0 = 0; k0 < K; k0 += 128) {
        __syncthreads();
#pragma unroll
        for (int i = 0; i < 4; ++i) {
            const unsigned char* gp = Abase + gA0 + (long)(i << 3) * ldaB + k0;
            unsigned char* lp = &As[(((wave << 5) + (i << 3)) << 7)];
            __builtin_amdgcn_global_load_lds((glb_uint*)gp, (lds_uint*)lp, 16, 0, 0);
        }
#pragma unroll
        for (int i = 0; i < 4; ++i) {
            const unsigned char* gp = Bbase + gB0 + (long)(i << 3) * ldbB + k0;
            unsigned char* lp = &Bs[(((wave << 5) + (i << 3)) << 7)];
            __builtin_amdgcn_global_load_lds((glb_uint*)gp, (lds_uint*)lp, 16, 0, 0);
        }
        __syncthreads();
#pragma unroll
        for (int ks = 0; ks < 4; ++ks) {
            long af[4], bg[4];
#pragma unroll
            for (int f = 0; f < 4; ++f) {
                const int m = wm + (f << 4) + m16;
                const int n = wn + (f << 4) + m16;
                const int c = (ks << 2) + quad;              // 8-byte chunk 0..15
                af[f] = *(const long*)&As[(m << 7) + ((c ^ ((m & 7) << 1)) << 3)];
                bg[f] = *(const long*)&Bs[(n << 7) + ((c ^ ((n & 7) << 1)) << 3)];
            }
#pragma unroll
            for (int fi = 0; fi < 4; ++fi)
#pragma unroll
                for (int fj = 0; fj < 4; ++fj)
                    acc[fi][fj] = __builtin_amdgcn_mfma_f32_16x16x32_fp8_fp8(
                        af[fi], bg[fj], acc[fi][fj], 0, 0, 0);
        }
    }

    const long zC = (long)blockIdx.z * sC;
#pragma unroll
    for (int fj = 0; fj < 4; ++fj) {
        const int col = n0 + wn + (fj << 4) + m16;
#pragma unroll
        for (int fi = 0; fi < 4; ++fi) {
#pragma unroll
            for (int r = 0; r < 4; ++r) {
                const int row = m0 + wm + (fi << 4) + (quad << 2) + r;
                outB[zC + (long)row * ldc + col] = f2bf(acc[fi][fj][r]);
            }
        }
    }
}

// ---------- launch ----------
extern "C" void kernel_launch(void* const* d_in, const int* in_sizes, int n_in,
                              void* d_out, int out_size, void* d_ws, size_t ws_size,
                              hipStream_t stream) {
    const float* x       = (const float*)d_in[0];
    const float* theta_w = (const float*)d_in[1];
    const float* theta_b = (const float*)d_in[2];
    const float* phi_w   = (const float*)d_in[3];
    const float* phi_b   = (const float*)d_in[4];
    const float* psi_w   = (const float*)d_in[5];
    const float* psi_b   = (const float*)d_in[6];
    const float* r1_w    = (const float*)d_in[7];
    const float* r1_b    = (const float*)d_in[8];
    const float* r2_w    = (const float*)d_in[9];
    const float* r2_b    = (const float*)d_in[10];
    float* out = (float*)d_out;

    constexpr int  N = 8, L = 2048, C = 512, H = 512, CH = 256;
    constexpr long NL = (long)N * L;  // 16384

    char* p = (char*)d_ws;
    auto alloc = [&](size_t bytes) { void* q = (void*)p; p += bytes; return q; };
    unsigned short* xb    = (unsigned short*)alloc(NL * C * 2);            // 16 MB
    unsigned short* xproj = (unsigned short*)alloc(NL * 1536 * 2);         // 48 MB
    unsigned short* xadd  = (unsigned short*)alloc(NL * H * 2);            // 16 MB
    unsigned short* h1    = (unsigned short*)alloc(NL * CH * 2);           //  8 MB
    unsigned short* wCatT = (unsigned short*)alloc((long)1536 * 512 * 2);  // 1.5 MB
    unsigned short* r1T   = (unsigned short*)alloc((long)H * CH * 2);
    unsigned short* r2T   = (unsigned short*)alloc((long)CH * C * 2);
    float*          bCat  = (float*)alloc(1536 * 4 + 256);
    unsigned short* S     = (unsigned short*)alloc((long)N * L * L * 2);   // 64 MB
    unsigned char*  VT8   = (unsigned char*)alloc((long)N * H * L);        //  8 MB

    // 1. prep: cast + weight transposes + bias concat
    prep<<<12294, 256, 0, stream>>>(x, theta_w, phi_w, psi_w, r1_w, r2_w,
                                    theta_b, phi_b, psi_b, xb, wCatT, r1T, r2T, bCat);

    // 2. merged projections: (16384x512) @ (512x1536) + bCat -> xproj bf16
    gemm128<0><<<dim3(NL / 128, 1536 / 128, 1), 256, 0, stream>>>(
        xb, wCatT, bCat, nullptr, xproj, nullptr, C, C, C, 1536, 0, 0, 0);

    // 3. V^T (fp8) per batch from psi slice
    transpose_v_fp8<<<dim3(H / 32, L / 32, N), 256, 0, stream>>>(xproj + 1024, VT8);

    // 4. S = phi @ theta^T (batched, bf16)
    gemm128<1><<<dim3(L / 128, L / 128, N), 256, 0, stream>>>(
        xproj + 512, xproj, nullptr, nullptr, S, nullptr, H, 1536, 1536, L,
        (long)L * 1536, (long)L * 1536, (long)L * L);

    // 5. softmax rows, bf16 -> fp8 in place
    softmax_fp8<<<dim3(L, N), 256, 0, stream>>>(S);

    // 6. x_add = P @ V (fp8 MFMA)
    gemm_pv_fp8<<<dim3(L / 128, H / 128, N), 256, 0, stream>>>(
        (const unsigned char*)S, VT8, xadd);

    // 7. h1 = leaky(x_add @ r1 + b)
    gemm128<2><<<dim3(NL / 128, CH / 128, 1), 256, 0, stream>>>(
        xadd, r1T, r1_b, nullptr, h1, nullptr, H, H, H, CH, 0, 0, 0);

    // 8. out = x + tanh(h1 @ r2 + b)
    gemm128<3><<<dim3(NL / 128, C / 128, 1), 256, 0, stream>>>(
        h1, r2T, r2_b, x, nullptr, out, CH, CH, CH, C, 0, 0, 0);
}

// Round 4
// 262.539 us; speedup vs baseline: 1.3456x; 1.0763x over previous
//
#include <hip/hip_runtime.h>
#include <hip/hip_bf16.h>

// ---------- types ----------
typedef __bf16 bf16x8 __attribute__((ext_vector_type(8)));
typedef float  f32x4  __attribute__((ext_vector_type(4)));
typedef __attribute__((address_space(3))) unsigned int       lds_uint;
typedef __attribute__((address_space(1))) const unsigned int glb_uint;

// ---------- helpers ----------
__device__ __forceinline__ unsigned short f2bf(float f) {
    unsigned int u = __float_as_uint(f);
    u += 0x7fffu + ((u >> 16) & 1u);   // RNE
    return (unsigned short)(u >> 16);
}
__device__ __forceinline__ float tanh_fast(float x) {
    float e = __expf(-2.0f * fabsf(x));
    float r = (1.0f - e) / (1.0f + e);
    return copysignf(r, x);
}
__device__ __forceinline__ unsigned char f2fp8(float v) {
    return (unsigned char)(__builtin_amdgcn_cvt_pk_fp8_f32(v, 0.0f, 0, false) & 0xff);
}

// ---------- prep: cast x->fp8, weights: proj->fp8(x16) transposed, r1/r2->bf16 T ----------
__global__ __launch_bounds__(256) void prep(
    const float* __restrict__ x,
    const float* __restrict__ theta_w, const float* __restrict__ phi_w,
    const float* __restrict__ psi_w,   const float* __restrict__ r1_w,
    const float* __restrict__ r2_w,
    const float* __restrict__ theta_b, const float* __restrict__ phi_b,
    const float* __restrict__ psi_b,
    unsigned char* __restrict__ xb8, unsigned char* __restrict__ wCat8T,
    unsigned short* __restrict__ r1T, unsigned short* __restrict__ r2T,
    float* __restrict__ bCat) {
    const int b = blockIdx.x, t = threadIdx.x;
    if (b < 8192) {                       // cast 8.39M floats -> fp8
        long i = ((long)b * 256 + t) * 4;
        float4 f = *(const float4*)(x + i);
        int w = __builtin_amdgcn_cvt_pk_fp8_f32(f.x, f.y, 0, false);
        w = __builtin_amdgcn_cvt_pk_fp8_f32(f.z, f.w, w, true);
        *(unsigned int*)(xb8 + i) = (unsigned int)w;
    } else if (b < 11264) {               // proj weights (512x512 each), x16, transposed
        const int sel = (b - 8192) >> 10;               // 0=theta,1=phi,2=psi
        const int idx = ((b - 8192) & 1023) * 256 + t;  // < 262144
        const float* w = sel == 0 ? theta_w : (sel == 1 ? phi_w : psi_w);
        const int r = idx >> 9, c = idx & 511;
        wCat8T[(long)(sel * 512 + c) * 512 + r] = f2fp8(w[idx] * 16.0f);
    } else if (b < 11776) {               // r1 (512x256) -> bf16 T
        const int idx = (b - 11264) * 256 + t;
        const int r = idx >> 8, c = idx & 255;
        r1T[(long)c * 512 + r] = f2bf(r1_w[idx]);
    } else if (b < 12288) {               // r2 (256x512) -> bf16 T
        const int idx = (b - 11776) * 256 + t;
        const int r = idx >> 9, c = idx & 511;
        r2T[(long)c * 256 + r] = f2bf(r2_w[idx]);
    } else {                              // bias concat (1536)
        const int i = (b - 12288) * 256 + t;
        if (i < 1536)
            bCat[i] = i < 512 ? theta_b[i] : (i < 1024 ? phi_b[i - 512] : psi_b[i - 1024]);
    }
}

// ---------- row softmax: read bf16 S row, write fp8 P in-place (first half of row) ----------
__global__ __launch_bounds__(256) void softmax_fp8(unsigned short* __restrict__ S) {
    const size_t row = (size_t)blockIdx.y * 2048 + blockIdx.x;
    unsigned short* p = S + row * 2048;
    const int t = threadIdx.x;
    uint4 raw = *(uint4*)(p + t * 8);
    unsigned int w[4] = {raw.x, raw.y, raw.z, raw.w};
    float v[8];
#pragma unroll
    for (int i = 0; i < 4; ++i) {
        v[2 * i]     = __uint_as_float((w[i] & 0xffffu) << 16);
        v[2 * i + 1] = __uint_as_float(w[i] & 0xffff0000u);
    }
    float mx = v[0];
#pragma unroll
    for (int i = 1; i < 8; ++i) mx = fmaxf(mx, v[i]);
#pragma unroll
    for (int off = 32; off > 0; off >>= 1) mx = fmaxf(mx, __shfl_xor(mx, off));
    __shared__ float red[8];
    const int wave = t >> 6, lane = t & 63;
    if (lane == 0) red[wave] = mx;
    __syncthreads();
    mx = fmaxf(fmaxf(red[0], red[1]), fmaxf(red[2], red[3]));
    float s = 0.0f;
#pragma unroll
    for (int i = 0; i < 8; ++i) { v[i] = __expf(v[i] - mx); s += v[i]; }
#pragma unroll
    for (int off = 32; off > 0; off >>= 1) s += __shfl_xor(s, off);
    if (lane == 0) red[4 + wave] = s;
    __syncthreads();
    s = red[4] + red[5] + red[6] + red[7];
    const float inv = 1.0f / s;
    int o0 = __builtin_amdgcn_cvt_pk_fp8_f32(v[0] * inv, v[1] * inv, 0, false);
    o0 = __builtin_amdgcn_cvt_pk_fp8_f32(v[2] * inv, v[3] * inv, o0, true);
    int o1 = __builtin_amdgcn_cvt_pk_fp8_f32(v[4] * inv, v[5] * inv, 0, false);
    o1 = __builtin_amdgcn_cvt_pk_fp8_f32(v[6] * inv, v[7] * inv, o1, true);
    uint2 ov; ov.x = (unsigned int)o0; ov.y = (unsigned int)o1;
    *(uint2*)((unsigned char*)p + t * 8) = ov;
}

// ---------- fp8 GEMM: 128x128 tile, BK=128 (proven R3 P@V structure, generalized) ----------
// C[m][n] = sum_k A[m][k]*Bt[n][k], A/Bt fp8, row pitches ldaB/ldbB bytes.
// MODE 0 (projection): v = acc/16 + bias[col]; write fp8 to outT/outP (contiguous,
//   pitch 512) or outV (V^T scatter: [z*512+col]*2048 + l) by col section.
// MODE 1: write bf16 outB, leading dim ldc.
template <int MODE>
__global__ __launch_bounds__(256) void gemm_fp8(
    const unsigned char* __restrict__ A,
    const unsigned char* __restrict__ Bt,
    const float* __restrict__ bias,
    unsigned short* __restrict__ outB,
    unsigned char* __restrict__ outT,
    unsigned char* __restrict__ outP,
    unsigned char* __restrict__ outV,
    int K, int ldaB, int ldbB, int ldc, long sA, long sB, long sC) {
    __shared__ unsigned char As[128 * 128];
    __shared__ unsigned char Bs[128 * 128];

    const int tid  = threadIdx.x;
    const int lane = tid & 63, wave = tid >> 6;
    const int m16  = lane & 15, quad = lane >> 4;
    const int wm   = (wave >> 1) << 6, wn = (wave & 1) << 6;
    const int m0   = blockIdx.x << 7, n0 = blockIdx.y << 7;

    const int srow = lane >> 3;
    const int uswz = (lane & 7) ^ srow;

    const unsigned char* Abase = A  + (long)blockIdx.z * sA + (long)m0 * ldaB;
    const unsigned char* Bbase = Bt + (long)blockIdx.z * sB + (long)n0 * ldbB;
    const int stR = (wave << 5) + srow;
    const long gA0 = (long)stR * ldaB + (uswz << 4);
    const long gB0 = (long)stR * ldbB + (uswz << 4);

    f32x4 acc[4][4] = {};

    for (int k0 = 0; k0 < K; k0 += 128) {
        __syncthreads();
#pragma unroll
        for (int i = 0; i < 4; ++i) {
            const unsigned char* gp = Abase + gA0 + (long)(i << 3) * ldaB + k0;
            unsigned char* lp = &As[(((wave << 5) + (i << 3)) << 7)];
            __builtin_amdgcn_global_load_lds((glb_uint*)gp, (lds_uint*)lp, 16, 0, 0);
        }
#pragma unroll
        for (int i = 0; i < 4; ++i) {
            const unsigned char* gp = Bbase + gB0 + (long)(i << 3) * ldbB + k0;
            unsigned char* lp = &Bs[(((wave << 5) + (i << 3)) << 7)];
            __builtin_amdgcn_global_load_lds((glb_uint*)gp, (lds_uint*)lp, 16, 0, 0);
        }
        __syncthreads();
#pragma unroll
        for (int ks = 0; ks < 4; ++ks) {
            long af[4], bg[4];
#pragma unroll
            for (int f = 0; f < 4; ++f) {
                const int m = wm + (f << 4) + m16;
                const int n = wn + (f << 4) + m16;
                const int c = (ks << 2) + quad;              // 8-byte chunk 0..15
                af[f] = *(const long*)&As[(m << 7) + ((c ^ ((m & 7) << 1)) << 3)];
                bg[f] = *(const long*)&Bs[(n << 7) + ((c ^ ((n & 7) << 1)) << 3)];
            }
#pragma unroll
            for (int fi = 0; fi < 4; ++fi)
#pragma unroll
                for (int fj = 0; fj < 4; ++fj)
                    acc[fi][fj] = __builtin_amdgcn_mfma_f32_16x16x32_fp8_fp8(
                        af[fi], bg[fj], acc[fi][fj], 0, 0, 0);
        }
    }

    const long zC = (long)blockIdx.z * sC;
#pragma unroll
    for (int fj = 0; fj < 4; ++fj) {
        const int col = n0 + wn + (fj << 4) + m16;
        float bv = 0.0f;
        if (MODE == 0) bv = bias[col];
#pragma unroll
        for (int fi = 0; fi < 4; ++fi) {
#pragma unroll
            for (int r = 0; r < 4; ++r) {
                const int row = m0 + wm + (fi << 4) + (quad << 2) + r;
                if (MODE == 0) {
                    const float v = acc[fi][fj][r] * 0.0625f + bv;   // W was x16
                    const unsigned char b8 = f2fp8(v);
                    const int sel = col >> 9, cb = col & 511;        // uniform per block
                    if (sel == 0)      outT[(long)row * 512 + cb] = b8;
                    else if (sel == 1) outP[(long)row * 512 + cb] = b8;
                    else {
                        const int z = row >> 11, l = row & 2047;
                        outV[((long)z * 512 + cb) * 2048 + l] = b8;  // V^T direct
                    }
                } else {
                    outB[zC + (long)row * ldc + col] = f2bf(acc[fi][fj][r]);
                }
            }
        }
    }
}

// ---------- 128x128-tile bt-form bf16 MFMA GEMM (MLP) ----------
// MODE 2: +bias, leaky(0.2) -> bf16 | MODE 3: +bias, tanh, +resid -> fp32
template <int MODE>
__global__ __launch_bounds__(256) void gemm128(
    const unsigned short* __restrict__ A,
    const unsigned short* __restrict__ Bt,
    const float* __restrict__ bias,
    const float* __restrict__ resid,
    unsigned short* __restrict__ outB,
    float* __restrict__ outF,
    int K, int lda, int ldb, int ldc) {
    __shared__ __bf16 As[128 * 64];
    __shared__ __bf16 Bs[128 * 64];

    const int tid  = threadIdx.x;
    const int lane = tid & 63, wave = tid >> 6;
    const int m16  = lane & 15, quad = lane >> 4;
    const int wm   = (wave >> 1) << 6, wn = (wave & 1) << 6;
    const int m0   = blockIdx.x << 7, n0 = blockIdx.y << 7;

    const int srow  = lane >> 3;
    const int uswz  = (lane & 7) ^ srow;

    const unsigned short* Abase = A  + (long)m0 * lda;
    const unsigned short* Bbase = Bt + (long)n0 * ldb;
    const int stR = (wave << 5) + srow;
    const long gA0 = (long)stR * lda + (uswz << 3);
    const long gB0 = (long)stR * ldb + (uswz << 3);

    f32x4 acc[4][4] = {};

    for (int k0 = 0; k0 < K; k0 += 64) {
        __syncthreads();
#pragma unroll
        for (int i = 0; i < 4; ++i) {
            const unsigned short* gp = Abase + gA0 + (long)(i << 3) * lda + k0;
            __bf16* lp = &As[(((wave << 5) + (i << 3)) << 6)];
            __builtin_amdgcn_global_load_lds((glb_uint*)gp, (lds_uint*)lp, 16, 0, 0);
        }
#pragma unroll
        for (int i = 0; i < 4; ++i) {
            const unsigned short* gp = Bbase + gB0 + (long)(i << 3) * ldb + k0;
            __bf16* lp = &Bs[(((wave << 5) + (i << 3)) << 6)];
            __builtin_amdgcn_global_load_lds((glb_uint*)gp, (lds_uint*)lp, 16, 0, 0);
        }
        __syncthreads();
#pragma unroll
        for (int ks = 0; ks < 2; ++ks) {
            bf16x8 af[4], bg[4];
#pragma unroll
            for (int f = 0; f < 4; ++f) {
                const int m  = wm + (f << 4) + m16;
                const int n  = wn + (f << 4) + m16;
                const int cu = (ks << 2) + quad;
                af[f] = *(const bf16x8*)&As[(m << 6) + ((cu ^ (m & 7)) << 3)];
                bg[f] = *(const bf16x8*)&Bs[(n << 6) + ((cu ^ (n & 7)) << 3)];
            }
#pragma unroll
            for (int fi = 0; fi < 4; ++fi)
#pragma unroll
                for (int fj = 0; fj < 4; ++fj)
                    acc[fi][fj] = __builtin_amdgcn_mfma_f32_16x16x32_bf16(
                        af[fi], bg[fj], acc[fi][fj], 0, 0, 0);
        }
    }

#pragma unroll
    for (int fj = 0; fj < 4; ++fj) {
        const int col = n0 + wn + (fj << 4) + m16;
        const float bv = bias[col];
#pragma unroll
        for (int fi = 0; fi < 4; ++fi) {
#pragma unroll
            for (int r = 0; r < 4; ++r) {
                const int row = m0 + wm + (fi << 4) + (quad << 2) + r;
                float v = acc[fi][fj][r] + bv;
                const long idx = (long)row * ldc + col;
                if (MODE == 2) {
                    v = v > 0.0f ? v : 0.2f * v;
                    outB[idx] = f2bf(v);
                } else {
                    outF[idx] = tanh_fast(v) + resid[idx];
                }
            }
        }
    }
}

// ---------- launch ----------
extern "C" void kernel_launch(void* const* d_in, const int* in_sizes, int n_in,
                              void* d_out, int out_size, void* d_ws, size_t ws_size,
                              hipStream_t stream) {
    const float* x       = (const float*)d_in[0];
    const float* theta_w = (const float*)d_in[1];
    const float* theta_b = (const float*)d_in[2];
    const float* phi_w   = (const float*)d_in[3];
    const float* phi_b   = (const float*)d_in[4];
    const float* psi_w   = (const float*)d_in[5];
    const float* psi_b   = (const float*)d_in[6];
    const float* r1_w    = (const float*)d_in[7];
    const float* r1_b    = (const float*)d_in[8];
    const float* r2_w    = (const float*)d_in[9];
    const float* r2_b    = (const float*)d_in[10];
    float* out = (float*)d_out;

    constexpr int  N = 8, L = 2048, C = 512, H = 512, CH = 256;
    constexpr long NL = (long)N * L;  // 16384

    char* p = (char*)d_ws;
    auto alloc = [&](size_t bytes) { void* q = (void*)p; p += bytes; return q; };
    unsigned char*  xb8    = (unsigned char*)alloc(NL * C);              //  8 MB
    unsigned char*  TH8    = (unsigned char*)alloc(NL * H);              //  8 MB (theta proj)
    unsigned char*  PH8    = (unsigned char*)alloc(NL * H);              //  8 MB (phi proj)
    unsigned char*  VT8    = (unsigned char*)alloc((long)N * H * L);     //  8 MB (psi^T)
    unsigned short* xadd   = (unsigned short*)alloc(NL * H * 2);         // 16 MB
    unsigned short* h1     = (unsigned short*)alloc(NL * CH * 2);        //  8 MB
    unsigned char*  wCat8T = (unsigned char*)alloc((long)1536 * 512);
    unsigned short* r1T    = (unsigned short*)alloc((long)H * CH * 2);
    unsigned short* r2T    = (unsigned short*)alloc((long)CH * C * 2);
    float*          bCat   = (float*)alloc(1536 * 4 + 256);
    unsigned short* S      = (unsigned short*)alloc((long)N * L * L * 2);  // 64 MB

    // 1. prep
    prep<<<12294, 256, 0, stream>>>(x, theta_w, phi_w, psi_w, r1_w, r2_w,
                                    theta_b, phi_b, psi_b, xb8, wCat8T, r1T, r2T, bCat);

    // 2. merged fp8 projections -> TH8, PH8, VT8 (V transposed in epilogue)
    gemm_fp8<0><<<dim3(NL / 128, 1536 / 128, 1), 256, 0, stream>>>(
        xb8, wCat8T, bCat, nullptr, TH8, PH8, VT8,
        C, C, C, 0, 0, 0, 0);

    // 3. S = phi @ theta^T (fp8 in, bf16 out)
    gemm_fp8<1><<<dim3(L / 128, L / 128, N), 256, 0, stream>>>(
        PH8, TH8, nullptr, S, nullptr, nullptr, nullptr,
        H, H, H, L, (long)L * H, (long)L * H, (long)L * L);

    // 4. softmax rows, bf16 -> fp8 in place
    softmax_fp8<<<dim3(L, N), 256, 0, stream>>>(S);

    // 5. x_add = P @ V (fp8; P rows at 4096-B pitch, V^T rows at 2048-B pitch)
    gemm_fp8<1><<<dim3(L / 128, H / 128, N), 256, 0, stream>>>(
        (const unsigned char*)S, VT8, nullptr, xadd, nullptr, nullptr, nullptr,
        L, 2 * L, L, H, (long)L * 2 * L, (long)H * L, (long)L * H);

    // 6. h1 = leaky(x_add @ r1 + b)  (bf16)
    gemm128<2><<<dim3(NL / 128, CH / 128, 1), 256, 0, stream>>>(
        xadd, r1T, r1_b, nullptr, h1, nullptr, H, H, H, CH);

    // 7. out = x + tanh(h1 @ r2 + b)  (bf16 in, fp32 out)
    gemm128<3><<<dim3(NL / 128, C / 128, 1), 256, 0, stream>>>(
        h1, r2T, r2_b, x, nullptr, out, CH, CH, CH, C);
}

// Round 5
// 245.082 us; speedup vs baseline: 1.4415x; 1.0712x over previous
//
#include <hip/hip_runtime.h>
#include <hip/hip_bf16.h>

// ---------- types ----------
typedef float f32x4 __attribute__((ext_vector_type(4)));
typedef __attribute__((address_space(3))) unsigned int       lds_uint;
typedef __attribute__((address_space(1))) const unsigned int glb_uint;

// ---------- helpers ----------
__device__ __forceinline__ float tanh_fast(float x) {
    float e = __expf(-2.0f * fabsf(x));
    float r = (1.0f - e) / (1.0f + e);
    return copysignf(r, x);
}
__device__ __forceinline__ unsigned char f2fp8(float v) {
    return (unsigned char)(__builtin_amdgcn_cvt_pk_fp8_f32(v, 0.0f, 0, false) & 0xff);
}
__device__ __forceinline__ unsigned short f2h(float v) {
    _Float16 h = (_Float16)v;
    unsigned short u;
    __builtin_memcpy(&u, &h, 2);
    return u;
}
__device__ __forceinline__ float h2f(unsigned short u) {
    _Float16 h;
    __builtin_memcpy(&h, &u, 2);
    return (float)h;
}

// ---------- prep: x->fp8; proj W ->fp8(x16) T; r1/r2 ->fp8(x16) T; bias concat ----------
__global__ __launch_bounds__(256) void prep(
    const float* __restrict__ x,
    const float* __restrict__ theta_w, const float* __restrict__ phi_w,
    const float* __restrict__ psi_w,   const float* __restrict__ r1_w,
    const float* __restrict__ r2_w,
    const float* __restrict__ theta_b, const float* __restrict__ phi_b,
    const float* __restrict__ psi_b,
    unsigned char* __restrict__ xb8, unsigned char* __restrict__ wCat8T,
    unsigned char* __restrict__ r1T8, unsigned char* __restrict__ r2T8,
    float* __restrict__ bCat) {
    const int b = blockIdx.x, t = threadIdx.x;
    if (b < 8192) {                       // cast x -> fp8
        long i = ((long)b * 256 + t) * 4;
        float4 f = *(const float4*)(x + i);
        int w = __builtin_amdgcn_cvt_pk_fp8_f32(f.x, f.y, 0, false);
        w = __builtin_amdgcn_cvt_pk_fp8_f32(f.z, f.w, w, true);
        *(unsigned int*)(xb8 + i) = (unsigned int)w;
    } else if (b < 11264) {               // proj weights (512x512 each), x16, transposed
        const int sel = (b - 8192) >> 10;
        const int idx = ((b - 8192) & 1023) * 256 + t;
        const float* w = sel == 0 ? theta_w : (sel == 1 ? phi_w : psi_w);
        const int r = idx >> 9, c = idx & 511;
        wCat8T[(long)(sel * 512 + c) * 512 + r] = f2fp8(w[idx] * 16.0f);
    } else if (b < 11776) {               // r1 (512x256) -> fp8 x16 T
        const int idx = (b - 11264) * 256 + t;
        const int r = idx >> 8, c = idx & 255;
        r1T8[(long)c * 512 + r] = f2fp8(r1_w[idx] * 16.0f);
    } else if (b < 12288) {               // r2 (256x512) -> fp8 x16 T
        const int idx = (b - 11776) * 256 + t;
        const int r = idx >> 9, c = idx & 511;
        r2T8[(long)c * 256 + r] = f2fp8(r2_w[idx] * 16.0f);
    } else {                              // bias concat (1536)
        const int i = (b - 12288) * 256 + t;
        if (i < 1536)
            bCat[i] = i < 512 ? theta_b[i] : (i < 1024 ? phi_b[i - 512] : psi_b[i - 1024]);
    }
}

// ---------- row softmax: read fp16 S row, write fp8 P in-place (first half of row) ----------
__global__ __launch_bounds__(256) void softmax_fp8(unsigned short* __restrict__ S) {
    const size_t row = (size_t)blockIdx.y * 2048 + blockIdx.x;
    unsigned short* p = S + row * 2048;
    const int t = threadIdx.x;
    uint4 raw = *(uint4*)(p + t * 8);
    unsigned int w[4] = {raw.x, raw.y, raw.z, raw.w};
    float v[8];
#pragma unroll
    for (int i = 0; i < 4; ++i) {
        v[2 * i]     = h2f((unsigned short)(w[i] & 0xffffu));
        v[2 * i + 1] = h2f((unsigned short)(w[i] >> 16));
    }
    float mx = v[0];
#pragma unroll
    for (int i = 1; i < 8; ++i) mx = fmaxf(mx, v[i]);
#pragma unroll
    for (int off = 32; off > 0; off >>= 1) mx = fmaxf(mx, __shfl_xor(mx, off));
    __shared__ float red[8];
    const int wave = t >> 6, lane = t & 63;
    if (lane == 0) red[wave] = mx;
    __syncthreads();
    mx = fmaxf(fmaxf(red[0], red[1]), fmaxf(red[2], red[3]));
    float s = 0.0f;
#pragma unroll
    for (int i = 0; i < 8; ++i) { v[i] = __expf(v[i] - mx); s += v[i]; }
#pragma unroll
    for (int off = 32; off > 0; off >>= 1) s += __shfl_xor(s, off);
    if (lane == 0) red[4 + wave] = s;
    __syncthreads();
    s = red[4] + red[5] + red[6] + red[7];
    const float inv = 1.0f / s;
    int o0 = __builtin_amdgcn_cvt_pk_fp8_f32(v[0] * inv, v[1] * inv, 0, false);
    o0 = __builtin_amdgcn_cvt_pk_fp8_f32(v[2] * inv, v[3] * inv, o0, true);
    int o1 = __builtin_amdgcn_cvt_pk_fp8_f32(v[4] * inv, v[5] * inv, 0, false);
    o1 = __builtin_amdgcn_cvt_pk_fp8_f32(v[6] * inv, v[7] * inv, o1, true);
    uint2 ov; ov.x = (unsigned int)o0; ov.y = (unsigned int)o1;
    *(uint2*)((unsigned char*)p + t * 8) = ov;   // after barrier 2; reads were before barrier 1
}

// ---------- fp8 GEMM: 128x128 tile, BK=128, global_load_lds staging ----------
// C[m][n] = sum_k A[m][k]*Bt[n][k]; A/Bt fp8, row pitches ldaB/ldbB bytes.
// MODE 0 proj:  v=acc/16+bCat[col]; col<1024 -> fp8 TH8/PH8 (pitch 512);
//               col>=1024 -> V^T (dword stores: 4 l-consecutive rows packed)
// MODE 1 qkt:   fp16 -> outH, ldc elems
// MODE 2 pv:    fp8  -> out8, pitch 512
// MODE 3 r1:    v=acc/16+bias; leaky 0.2; fp8 -> out8, pitch 256
// MODE 4 r2:    v=acc/16+bias; tanh; +resid; fp32 -> outF, ldc 512
template <int MODE>
__global__ __launch_bounds__(256) void gemm_fp8(
    const unsigned char* __restrict__ A,
    const unsigned char* __restrict__ Bt,
    const float* __restrict__ bias,
    const float* __restrict__ resid,
    unsigned short* __restrict__ outH,
    unsigned char* __restrict__ out8,
    unsigned char* __restrict__ out8b,
    unsigned char* __restrict__ outV,
    float* __restrict__ outF,
    int K, int ldaB, int ldbB, int ldc, long sA, long sB, long sC) {
    __shared__ unsigned char As[128 * 128];
    __shared__ unsigned char Bs[128 * 128];

    const int tid  = threadIdx.x;
    const int lane = tid & 63, wave = tid >> 6;
    const int m16  = lane & 15, quad = lane >> 4;
    const int wm   = (wave >> 1) << 6, wn = (wave & 1) << 6;
    const int m0   = blockIdx.x << 7, n0 = blockIdx.y << 7;

    const int srow = lane >> 3;
    const int uswz = (lane & 7) ^ srow;

    const unsigned char* Abase = A  + (long)blockIdx.z * sA + (long)m0 * ldaB;
    const unsigned char* Bbase = Bt + (long)blockIdx.z * sB + (long)n0 * ldbB;
    const int stR = (wave << 5) + srow;
    const long gA0 = (long)stR * ldaB + (uswz << 4);
    const long gB0 = (long)stR * ldbB + (uswz << 4);

    f32x4 acc[4][4] = {};

    for (int k0 = 0; k0 < K; k0 += 128) {
        __syncthreads();
#pragma unroll
        for (int i = 0; i < 4; ++i) {
            const unsigned char* gp = Abase + gA0 + (long)(i << 3) * ldaB + k0;
            unsigned char* lp = &As[(((wave << 5) + (i << 3)) << 7)];
            __builtin_amdgcn_global_load_lds((glb_uint*)gp, (lds_uint*)lp, 16, 0, 0);
        }
#pragma unroll
        for (int i = 0; i < 4; ++i) {
            const unsigned char* gp = Bbase + gB0 + (long)(i << 3) * ldbB + k0;
            unsigned char* lp = &Bs[(((wave << 5) + (i << 3)) << 7)];
            __builtin_amdgcn_global_load_lds((glb_uint*)gp, (lds_uint*)lp, 16, 0, 0);
        }
        __syncthreads();
#pragma unroll
        for (int ks = 0; ks < 4; ++ks) {
            long af[4], bg[4];
#pragma unroll
            for (int f = 0; f < 4; ++f) {
                const int m = wm + (f << 4) + m16;
                const int n = wn + (f << 4) + m16;
                const int c = (ks << 2) + quad;
                af[f] = *(const long*)&As[(m << 7) + ((c ^ ((m & 7) << 1)) << 3)];
                bg[f] = *(const long*)&Bs[(n << 7) + ((c ^ ((n & 7) << 1)) << 3)];
            }
#pragma unroll
            for (int fi = 0; fi < 4; ++fi)
#pragma unroll
                for (int fj = 0; fj < 4; ++fj)
                    acc[fi][fj] = __builtin_amdgcn_mfma_f32_16x16x32_fp8_fp8(
                        af[fi], bg[fj], acc[fi][fj], 0, 0, 0);
        }
    }

    const long zC = (long)blockIdx.z * sC;

    if (MODE == 0) {
        const int sel = n0 >> 9;                         // block-uniform
        if (sel < 2) {
            unsigned char* dst = sel == 0 ? out8 : out8b;
#pragma unroll
            for (int fj = 0; fj < 4; ++fj) {
                const int col = n0 + wn + (fj << 4) + m16;
                const int cb  = col & 511;
                const float bv = bias[col];
#pragma unroll
                for (int fi = 0; fi < 4; ++fi)
#pragma unroll
                    for (int r = 0; r < 4; ++r) {
                        const int row = m0 + wm + (fi << 4) + (quad << 2) + r;
                        dst[(long)row * 512 + cb] = f2fp8(acc[fi][fj][r] * 0.0625f + bv);
                    }
            }
        } else {                                         // V^T: pack 4 l-rows per dword
            const int z = m0 >> 11, l0 = (m0 & 2047) + wm + (quad << 2);
#pragma unroll
            for (int fj = 0; fj < 4; ++fj) {
                const int col = n0 + wn + (fj << 4) + m16;
                const int h   = col & 511;
                const float bv = bias[col];
#pragma unroll
                for (int fi = 0; fi < 4; ++fi) {
                    int w = __builtin_amdgcn_cvt_pk_fp8_f32(
                        acc[fi][fj][0] * 0.0625f + bv, acc[fi][fj][1] * 0.0625f + bv, 0, false);
                    w = __builtin_amdgcn_cvt_pk_fp8_f32(
                        acc[fi][fj][2] * 0.0625f + bv, acc[fi][fj][3] * 0.0625f + bv, w, true);
                    *(unsigned int*)(outV + ((long)z * 512 + h) * 2048 + l0 + (fi << 4)) =
                        (unsigned int)w;
                }
            }
        }
    } else {
#pragma unroll
        for (int fj = 0; fj < 4; ++fj) {
            const int col = n0 + wn + (fj << 4) + m16;
            float bv = 0.0f;
            if (MODE >= 3) bv = bias[col];
#pragma unroll
            for (int fi = 0; fi < 4; ++fi)
#pragma unroll
                for (int r = 0; r < 4; ++r) {
                    const int row = m0 + wm + (fi << 4) + (quad << 2) + r;
                    float v = acc[fi][fj][r];
                    if (MODE == 1) {
                        outH[zC + (long)row * ldc + col] = f2h(v);
                    } else if (MODE == 2) {
                        out8[zC + (long)row * 512 + col] = f2fp8(v);
                    } else if (MODE == 3) {
                        v = v * 0.0625f + bv;
                        v = v > 0.0f ? v : 0.2f * v;
                        out8[(long)row * 256 + col] = f2fp8(v);
                    } else {
                        v = v * 0.0625f + bv;
                        const long idx = (long)row * ldc + col;
                        outF[idx] = tanh_fast(v) + resid[idx];
                    }
                }
        }
    }
}

// ---------- launch ----------
extern "C" void kernel_launch(void* const* d_in, const int* in_sizes, int n_in,
                              void* d_out, int out_size, void* d_ws, size_t ws_size,
                              hipStream_t stream) {
    const float* x       = (const float*)d_in[0];
    const float* theta_w = (const float*)d_in[1];
    const float* theta_b = (const float*)d_in[2];
    const float* phi_w   = (const float*)d_in[3];
    const float* phi_b   = (const float*)d_in[4];
    const float* psi_w   = (const float*)d_in[5];
    const float* psi_b   = (const float*)d_in[6];
    const float* r1_w    = (const float*)d_in[7];
    const float* r1_b    = (const float*)d_in[8];
    const float* r2_w    = (const float*)d_in[9];
    const float* r2_b    = (const float*)d_in[10];
    float* out = (float*)d_out;

    constexpr int  N = 8, L = 2048, C = 512, H = 512, CH = 256;
    constexpr long NL = (long)N * L;  // 16384

    char* p = (char*)d_ws;
    auto alloc = [&](size_t bytes) { void* q = (void*)p; p += bytes; return q; };
    unsigned char*  xb8    = (unsigned char*)alloc(NL * C);            //  8 MB
    unsigned char*  TH8    = (unsigned char*)alloc(NL * H);            //  8 MB
    unsigned char*  PH8    = (unsigned char*)alloc(NL * H);            //  8 MB
    unsigned char*  VT8    = (unsigned char*)alloc((long)N * H * L);   //  8 MB
    unsigned char*  xadd8  = (unsigned char*)alloc(NL * H);            //  8 MB
    unsigned char*  h18    = (unsigned char*)alloc(NL * CH);           //  4 MB
    unsigned char*  wCat8T = (unsigned char*)alloc((long)1536 * 512);
    unsigned char*  r1T8   = (unsigned char*)alloc((long)H * CH);
    unsigned char*  r2T8   = (unsigned char*)alloc((long)CH * C);
    float*          bCat   = (float*)alloc(1536 * 4 + 256);
    unsigned short* S      = (unsigned short*)alloc((long)N * L * L * 2);  // 64 MB fp16/P-fp8

    // 1. prep
    prep<<<12294, 256, 0, stream>>>(x, theta_w, phi_w, psi_w, r1_w, r2_w,
                                    theta_b, phi_b, psi_b, xb8, wCat8T, r1T8, r2T8, bCat);

    // 2. merged fp8 projections -> TH8, PH8, VT8 (V^T via packed dword stores)
    gemm_fp8<0><<<dim3(NL / 128, 1536 / 128, 1), 256, 0, stream>>>(
        xb8, wCat8T, bCat, nullptr, nullptr, TH8, PH8, VT8, nullptr,
        C, C, C, 0, 0, 0, 0);

    // 3. S = phi @ theta^T (fp8 in, fp16 out)
    gemm_fp8<1><<<dim3(L / 128, L / 128, N), 256, 0, stream>>>(
        PH8, TH8, nullptr, nullptr, S, nullptr, nullptr, nullptr, nullptr,
        H, H, H, L, (long)L * H, (long)L * H, (long)L * L);

    // 4. softmax rows, fp16 -> fp8 in place
    softmax_fp8<<<dim3(L, N), 256, 0, stream>>>(S);

    // 5. x_add = P @ V (fp8; P rows at 4096-B pitch, V^T rows at 2048-B pitch) -> fp8
    gemm_fp8<2><<<dim3(L / 128, H / 128, N), 256, 0, stream>>>(
        (const unsigned char*)S, VT8, nullptr, nullptr, nullptr, xadd8, nullptr, nullptr, nullptr,
        L, 2 * L, L, H, (long)L * 2 * L, (long)H * L, (long)L * H);

    // 6. h1 = leaky(x_add @ r1 + b) -> fp8
    gemm_fp8<3><<<dim3(NL / 128, CH / 128, 1), 256, 0, stream>>>(
        xadd8, r1T8, r1_b, nullptr, nullptr, h18, nullptr, nullptr, nullptr,
        H, H, H, CH, 0, 0, 0);

    // 7. out = x + tanh(h1 @ r2 + b) -> fp32
    gemm_fp8<4><<<dim3(NL / 128, C / 128, 1), 256, 0, stream>>>(
        h18, r2T8, r2_b, x, nullptr, nullptr, nullptr, nullptr, out,
        CH, CH, CH, C, 0, 0, 0);
}

// Round 6
// 236.439 us; speedup vs baseline: 1.4942x; 1.0366x over previous
//
#include <hip/hip_runtime.h>
#include <hip/hip_bf16.h>

// ---------- types ----------
typedef float f32x4 __attribute__((ext_vector_type(4)));
typedef int   v8i   __attribute__((ext_vector_type(8)));
typedef __attribute__((address_space(3))) unsigned int       lds_uint;
typedef __attribute__((address_space(1))) const unsigned int glb_uint;

// ---------- helpers ----------
__device__ __forceinline__ float tanh_fast(float x) {
    float e = __expf(-2.0f * fabsf(x));
    float r = (1.0f - e) / (1.0f + e);
    return copysignf(r, x);
}
__device__ __forceinline__ unsigned char f2fp8(float v) {
    return (unsigned char)(__builtin_amdgcn_cvt_pk_fp8_f32(v, 0.0f, 0, false) & 0xff);
}
__device__ __forceinline__ unsigned short f2h(float v) {
    _Float16 h = (_Float16)v;
    unsigned short u;
    __builtin_memcpy(&u, &h, 2);
    return u;
}
__device__ __forceinline__ float h2f(unsigned short u) {
    _Float16 h;
    __builtin_memcpy(&h, &u, 2);
    return (float)h;
}

// ---------- prep: x->fp8; proj W ->fp8(x16) T; r1/r2 ->fp8(x16) T; bias concat ----------
__global__ __launch_bounds__(256) void prep(
    const float* __restrict__ x,
    const float* __restrict__ theta_w, const float* __restrict__ phi_w,
    const float* __restrict__ psi_w,   const float* __restrict__ r1_w,
    const float* __restrict__ r2_w,
    const float* __restrict__ theta_b, const float* __restrict__ phi_b,
    const float* __restrict__ psi_b,
    unsigned char* __restrict__ xb8, unsigned char* __restrict__ wCat8T,
    unsigned char* __restrict__ r1T8, unsigned char* __restrict__ r2T8,
    float* __restrict__ bCat) {
    const int b = blockIdx.x, t = threadIdx.x;
    if (b < 8192) {                       // cast x -> fp8
        long i = ((long)b * 256 + t) * 4;
        float4 f = *(const float4*)(x + i);
        int w = __builtin_amdgcn_cvt_pk_fp8_f32(f.x, f.y, 0, false);
        w = __builtin_amdgcn_cvt_pk_fp8_f32(f.z, f.w, w, true);
        *(unsigned int*)(xb8 + i) = (unsigned int)w;
    } else if (b < 11264) {               // proj weights (512x512 each), x16, transposed
        const int sel = (b - 8192) >> 10;
        const int idx = ((b - 8192) & 1023) * 256 + t;
        const float* w = sel == 0 ? theta_w : (sel == 1 ? phi_w : psi_w);
        const int r = idx >> 9, c = idx & 511;
        wCat8T[(long)(sel * 512 + c) * 512 + r] = f2fp8(w[idx] * 16.0f);
    } else if (b < 11776) {               // r1 (512x256) -> fp8 x16 T
        const int idx = (b - 11264) * 256 + t;
        const int r = idx >> 8, c = idx & 255;
        r1T8[(long)c * 512 + r] = f2fp8(r1_w[idx] * 16.0f);
    } else if (b < 12288) {               // r2 (256x512) -> fp8 x16 T
        const int idx = (b - 11776) * 256 + t;
        const int r = idx >> 9, c = idx & 511;
        r2T8[(long)c * 256 + r] = f2fp8(r2_w[idx] * 16.0f);
    } else {                              // bias concat (1536)
        const int i = (b - 12288) * 256 + t;
        if (i < 1536)
            bCat[i] = i < 512 ? theta_b[i] : (i < 1024 ? phi_b[i - 512] : psi_b[i - 1024]);
    }
}

// ---------- row softmax: read fp16 S row, write fp8 P in-place (first half of row) ----------
__global__ __launch_bounds__(256) void softmax_fp8(unsigned short* __restrict__ S) {
    const size_t row = (size_t)blockIdx.y * 2048 + blockIdx.x;
    unsigned short* p = S + row * 2048;
    const int t = threadIdx.x;
    uint4 raw = *(uint4*)(p + t * 8);
    unsigned int w[4] = {raw.x, raw.y, raw.z, raw.w};
    float v[8];
#pragma unroll
    for (int i = 0; i < 4; ++i) {
        v[2 * i]     = h2f((unsigned short)(w[i] & 0xffffu));
        v[2 * i + 1] = h2f((unsigned short)(w[i] >> 16));
    }
    float mx = v[0];
#pragma unroll
    for (int i = 1; i < 8; ++i) mx = fmaxf(mx, v[i]);
#pragma unroll
    for (int off = 32; off > 0; off >>= 1) mx = fmaxf(mx, __shfl_xor(mx, off));
    __shared__ float red[8];
    const int wave = t >> 6, lane = t & 63;
    if (lane == 0) red[wave] = mx;
    __syncthreads();
    mx = fmaxf(fmaxf(red[0], red[1]), fmaxf(red[2], red[3]));
    float s = 0.0f;
#pragma unroll
    for (int i = 0; i < 8; ++i) { v[i] = __expf(v[i] - mx); s += v[i]; }
#pragma unroll
    for (int off = 32; off > 0; off >>= 1) s += __shfl_xor(s, off);
    if (lane == 0) red[4 + wave] = s;
    __syncthreads();
    s = red[4] + red[5] + red[6] + red[7];
    const float inv = 1.0f / s;
    int o0 = __builtin_amdgcn_cvt_pk_fp8_f32(v[0] * inv, v[1] * inv, 0, false);
    o0 = __builtin_amdgcn_cvt_pk_fp8_f32(v[2] * inv, v[3] * inv, o0, true);
    int o1 = __builtin_amdgcn_cvt_pk_fp8_f32(v[4] * inv, v[5] * inv, 0, false);
    o1 = __builtin_amdgcn_cvt_pk_fp8_f32(v[6] * inv, v[7] * inv, o1, true);
    uint2 ov; ov.x = (unsigned int)o0; ov.y = (unsigned int)o1;
    *(uint2*)((unsigned char*)p + t * 8) = ov;   // after barrier 2; reads were before barrier 1
}

// ---------- fp8 GEMM: 128x128 tile, BK=128, MX-scaled K=128 MFMA (unit scales) ----------
// C[m][n] = sum_k A[m][k]*Bt[n][k]; A/Bt fp8, row pitches ldaB/ldbB bytes.
// MODE 0 proj:  v=acc/16+bCat[col]; col<1024 -> fp8 TH8/PH8 (pitch 512);
//               col>=1024 -> V^T (dword stores: 4 l-consecutive rows packed)
// MODE 1 qkt:   fp16 -> outH, ldc elems
// MODE 2 pv:    fp8  -> out8, pitch 512
// MODE 3 r1:    v=acc/16+bias; leaky 0.2; fp8 -> out8, pitch 256
// MODE 4 r2:    v=acc/16+bias; tanh; +resid; fp32 -> outF, ldc 512
template <int MODE>
__global__ __launch_bounds__(256) void gemm_fp8(
    const unsigned char* __restrict__ A,
    const unsigned char* __restrict__ Bt,
    const float* __restrict__ bias,
    const float* __restrict__ resid,
    unsigned short* __restrict__ outH,
    unsigned char* __restrict__ out8,
    unsigned char* __restrict__ out8b,
    unsigned char* __restrict__ outV,
    float* __restrict__ outF,
    int K, int ldaB, int ldbB, int ldc, long sA, long sB, long sC) {
    __shared__ unsigned char As[128 * 128];
    __shared__ unsigned char Bs[128 * 128];

    const int tid  = threadIdx.x;
    const int lane = tid & 63, wave = tid >> 6;
    const int m16  = lane & 15, quad = lane >> 4;
    const int wm   = (wave >> 1) << 6, wn = (wave & 1) << 6;
    const int m0   = blockIdx.x << 7, n0 = blockIdx.y << 7;

    const int srow = lane >> 3;
    const int uswz = (lane & 7) ^ srow;

    const unsigned char* Abase = A  + (long)blockIdx.z * sA + (long)m0 * ldaB;
    const unsigned char* Bbase = Bt + (long)blockIdx.z * sB + (long)n0 * ldbB;
    const int stR = (wave << 5) + srow;
    const long gA0 = (long)stR * ldaB + (uswz << 4);
    const long gB0 = (long)stR * ldbB + (uswz << 4);

    f32x4 acc[4][4] = {};

    union F8 { v8i v; long l[4]; };

    for (int k0 = 0; k0 < K; k0 += 128) {
        __syncthreads();
#pragma unroll
        for (int i = 0; i < 4; ++i) {
            const unsigned char* gp = Abase + gA0 + (long)(i << 3) * ldaB + k0;
            unsigned char* lp = &As[(((wave << 5) + (i << 3)) << 7)];
            __builtin_amdgcn_global_load_lds((glb_uint*)gp, (lds_uint*)lp, 16, 0, 0);
        }
#pragma unroll
        for (int i = 0; i < 4; ++i) {
            const unsigned char* gp = Bbase + gB0 + (long)(i << 3) * ldbB + k0;
            unsigned char* lp = &Bs[(((wave << 5) + (i << 3)) << 7)];
            __builtin_amdgcn_global_load_lds((glb_uint*)gp, (lds_uint*)lp, 16, 0, 0);
        }
        __syncthreads();
        // MX-scaled K=128 MFMA: lane holds A[m][k=quad*32 .. +31] (4 swizzled b64 chunks)
        F8 af[4], bg[4];
#pragma unroll
        for (int f = 0; f < 4; ++f) {
            const int m = wm + (f << 4) + m16;
            const int n = wn + (f << 4) + m16;
#pragma unroll
            for (int j = 0; j < 4; ++j) {
                const int c = (quad << 2) + j;              // 8-byte chunk 0..15
                af[f].l[j] = *(const long*)&As[(m << 7) + ((c ^ ((m & 7) << 1)) << 3)];
                bg[f].l[j] = *(const long*)&Bs[(n << 7) + ((c ^ ((n & 7) << 1)) << 3)];
            }
        }
#pragma unroll
        for (int fi = 0; fi < 4; ++fi)
#pragma unroll
            for (int fj = 0; fj < 4; ++fj)
                acc[fi][fj] = __builtin_amdgcn_mfma_scale_f32_16x16x128_f8f6f4(
                    af[fi].v, bg[fj].v, acc[fi][fj],
                    0, 0,            // cbsz=0 (A=e4m3), blgp=0 (B=e4m3)
                    0, 127,          // A scale: opsel 0, E8M0 127 = 1.0
                    0, 127);         // B scale: 1.0
    }

    const long zC = (long)blockIdx.z * sC;

    if (MODE == 0) {
        const int sel = n0 >> 9;                         // block-uniform
        if (sel < 2) {
            unsigned char* dst = sel == 0 ? out8 : out8b;
#pragma unroll
            for (int fj = 0; fj < 4; ++fj) {
                const int col = n0 + wn + (fj << 4) + m16;
                const int cb  = col & 511;
                const float bv = bias[col];
#pragma unroll
                for (int fi = 0; fi < 4; ++fi)
#pragma unroll
                    for (int r = 0; r < 4; ++r) {
                        const int row = m0 + wm + (fi << 4) + (quad << 2) + r;
                        dst[(long)row * 512 + cb] = f2fp8(acc[fi][fj][r] * 0.0625f + bv);
                    }
            }
        } else {                                         // V^T: pack 4 l-rows per dword
            const int z = m0 >> 11, l0 = (m0 & 2047) + wm + (quad << 2);
#pragma unroll
            for (int fj = 0; fj < 4; ++fj) {
                const int col = n0 + wn + (fj << 4) + m16;
                const int h   = col & 511;
                const float bv = bias[col];
#pragma unroll
                for (int fi = 0; fi < 4; ++fi) {
                    int w = __builtin_amdgcn_cvt_pk_fp8_f32(
                        acc[fi][fj][0] * 0.0625f + bv, acc[fi][fj][1] * 0.0625f + bv, 0, false);
                    w = __builtin_amdgcn_cvt_pk_fp8_f32(
                        acc[fi][fj][2] * 0.0625f + bv, acc[fi][fj][3] * 0.0625f + bv, w, true);
                    *(unsigned int*)(outV + ((long)z * 512 + h) * 2048 + l0 + (fi << 4)) =
                        (unsigned int)w;
                }
            }
        }
    } else {
#pragma unroll
        for (int fj = 0; fj < 4; ++fj) {
            const int col = n0 + wn + (fj << 4) + m16;
            float bv = 0.0f;
            if (MODE >= 3) bv = bias[col];
#pragma unroll
            for (int fi = 0; fi < 4; ++fi)
#pragma unroll
                for (int r = 0; r < 4; ++r) {
                    const int row = m0 + wm + (fi << 4) + (quad << 2) + r;
                    float v = acc[fi][fj][r];
                    if (MODE == 1) {
                        outH[zC + (long)row * ldc + col] = f2h(v);
                    } else if (MODE == 2) {
                        out8[zC + (long)row * 512 + col] = f2fp8(v);
                    } else if (MODE == 3) {
                        v = v * 0.0625f + bv;
                        v = v > 0.0f ? v : 0.2f * v;
                        out8[(long)row * 256 + col] = f2fp8(v);
                    } else {
                        v = v * 0.0625f + bv;
                        const long idx = (long)row * ldc + col;
                        outF[idx] = tanh_fast(v) + resid[idx];
                    }
                }
        }
    }
}

// ---------- launch ----------
extern "C" void kernel_launch(void* const* d_in, const int* in_sizes, int n_in,
                              void* d_out, int out_size, void* d_ws, size_t ws_size,
                              hipStream_t stream) {
    const float* x       = (const float*)d_in[0];
    const float* theta_w = (const float*)d_in[1];
    const float* theta_b = (const float*)d_in[2];
    const float* phi_w   = (const float*)d_in[3];
    const float* phi_b   = (const float*)d_in[4];
    const float* psi_w   = (const float*)d_in[5];
    const float* psi_b   = (const float*)d_in[6];
    const float* r1_w    = (const float*)d_in[7];
    const float* r1_b    = (const float*)d_in[8];
    const float* r2_w    = (const float*)d_in[9];
    const float* r2_b    = (const float*)d_in[10];
    float* out = (float*)d_out;

    constexpr int  N = 8, L = 2048, C = 512, H = 512, CH = 256;
    constexpr long NL = (long)N * L;  // 16384

    char* p = (char*)d_ws;
    auto alloc = [&](size_t bytes) { void* q = (void*)p; p += bytes; return q; };
    unsigned char*  xb8    = (unsigned char*)alloc(NL * C);            //  8 MB
    unsigned char*  TH8    = (unsigned char*)alloc(NL * H);            //  8 MB
    unsigned char*  PH8    = (unsigned char*)alloc(NL * H);            //  8 MB
    unsigned char*  VT8    = (unsigned char*)alloc((long)N * H * L);   //  8 MB
    unsigned char*  xadd8  = (unsigned char*)alloc(NL * H);            //  8 MB
    unsigned char*  h18    = (unsigned char*)alloc(NL * CH);           //  4 MB
    unsigned char*  wCat8T = (unsigned char*)alloc((long)1536 * 512);
    unsigned char*  r1T8   = (unsigned char*)alloc((long)H * CH);
    unsigned char*  r2T8   = (unsigned char*)alloc((long)CH * C);
    float*          bCat   = (float*)alloc(1536 * 4 + 256);
    unsigned short* S      = (unsigned short*)alloc((long)N * L * L * 2);  // 64 MB fp16/P-fp8

    // 1. prep
    prep<<<12294, 256, 0, stream>>>(x, theta_w, phi_w, psi_w, r1_w, r2_w,
                                    theta_b, phi_b, psi_b, xb8, wCat8T, r1T8, r2T8, bCat);

    // 2. merged fp8 projections -> TH8, PH8, VT8 (V^T via packed dword stores)
    gemm_fp8<0><<<dim3(NL / 128, 1536 / 128, 1), 256, 0, stream>>>(
        xb8, wCat8T, bCat, nullptr, nullptr, TH8, PH8, VT8, nullptr,
        C, C, C, 0, 0, 0, 0);

    // 3. S = phi @ theta^T (fp8 in, fp16 out)
    gemm_fp8<1><<<dim3(L / 128, L / 128, N), 256, 0, stream>>>(
        PH8, TH8, nullptr, nullptr, S, nullptr, nullptr, nullptr, nullptr,
        H, H, H, L, (long)L * H, (long)L * H, (long)L * L);

    // 4. softmax rows, fp16 -> fp8 in place
    softmax_fp8<<<dim3(L, N), 256, 0, stream>>>(S);

    // 5. x_add = P @ V (fp8; P rows at 4096-B pitch, V^T rows at 2048-B pitch) -> fp8
    gemm_fp8<2><<<dim3(L / 128, H / 128, N), 256, 0, stream>>>(
        (const unsigned char*)S, VT8, nullptr, nullptr, nullptr, xadd8, nullptr, nullptr, nullptr,
        L, 2 * L, L, H, (long)L * 2 * L, (long)H * L, (long)L * H);

    // 6. h1 = leaky(x_add @ r1 + b) -> fp8
    gemm_fp8<3><<<dim3(NL / 128, CH / 128, 1), 256, 0, stream>>>(
        xadd8, r1T8, r1_b, nullptr, nullptr, h18, nullptr, nullptr, nullptr,
        H, H, H, CH, 0, 0, 0);

    // 7. out = x + tanh(h1 @ r2 + b) -> fp32
    gemm_fp8<4><<<dim3(NL / 128, C / 128, 1), 256, 0, stream>>>(
        h18, r2T8, r2_b, x, nullptr, nullptr, nullptr, nullptr, out,
        CH, CH, CH, C, 0, 0, 0);
}